// Round 16
// baseline (301.797 us; speedup 1.0000x reference)
//
#include <hip/hip_runtime.h>

namespace {

typedef unsigned short ushort_t;
typedef short s16x8 __attribute__((ext_vector_type(8)));
typedef float f32x4 __attribute__((ext_vector_type(4)));

constexpr int B_ = 2, C_ = 64, H_ = 192, W_ = 192;
constexpr int C4 = 256;
constexpr int NPIX = H_ * W_;                       // 36864
constexpr size_t NT = (size_t)B_ * C4 * NPIX;       // 18,874,368
constexpr int PB = NPIX / 32;                       // 1152 32-pixel blocks per batch
constexpr int PB16 = NPIX / 16;                     // 2304 16-pixel strips per batch
constexpr int NTILE = B_ * PB16;                    // 4608 tiles
constexpr int NBLK3 = 512;                          // persistent blocks (9 tiles each)
constexpr float EPSV = 1e-20f;

constexpr int TILEW = 32, TILEH = 16;
constexpr int TLX = TILEW + 2;   // 34
constexpr int TLY = TILEH + 2;   // 18

__device__ __forceinline__ ushort_t f2bu(float x) {
    union { float f; unsigned u; } v; v.f = x;
    unsigned r = v.u + 0x7fffu + ((v.u >> 16) & 1u);   // RNE to bf16
    return (ushort_t)(r >> 16);
}
__device__ __forceinline__ float bu2f(ushort_t h) {
    union { unsigned u; float f; } v; v.u = ((unsigned)h) << 16;
    return v.f;
}

__device__ __forceinline__ void async_ld16(const ushort_t* g, ushort_t* l) {
    __builtin_amdgcn_global_load_lds(
        (const __attribute__((address_space(1))) unsigned int*)g,
        (__attribute__((address_space(3))) unsigned int*)l, 16, 0, 0);
}

// ---------------- cw -> split bf16 hi/lo + per-block cw partial sums ----------
__global__ __launch_bounds__(256) void k_prep(const float* __restrict__ cw,
                                              ushort_t* __restrict__ cwH,
                                              ushort_t* __restrict__ cwL,
                                              float* __restrict__ partial) {
    __shared__ float red[256];
    int tid = threadIdx.x;
    int i = blockIdx.x * 256 + tid;   // grid 256 -> 65536
    float w = cw[i];
    ushort_t h = f2bu(w);
    cwH[i] = h;
    cwL[i] = f2bu(w - bu2f(h));
    red[tid] = w; __syncthreads();
    for (int s2 = 128; s2 > 0; s2 >>= 1) { if (tid < s2) red[tid] += red[tid + s2]; __syncthreads(); }
    if (tid == 0) partial[blockIdx.x] = red[0];
}

// ---------------- tiny final reduction: sw sum + cw partials ----------------
__global__ __launch_bounds__(256) void k_sums2(const float* __restrict__ sw,
                                               const float* __restrict__ partial,
                                               float* __restrict__ sums) {
    __shared__ float red[256];
    int tid = threadIdx.x;
    float a = 0.f;
    for (int i = tid; i < C4 * 9; i += 256) a += sw[i];
    red[tid] = a; __syncthreads();
    for (int s2 = 128; s2 > 0; s2 >>= 1) { if (tid < s2) red[tid] += red[tid + s2]; __syncthreads(); }
    if (tid == 0) sums[0] = red[0];
    __syncthreads();
    red[tid] = partial[tid]; __syncthreads();
    for (int s2 = 128; s2 > 0; s2 >>= 1) { if (tid < s2) red[tid] += red[tid + s2]; __syncthreads(); }
    if (tid == 0) sums[1] = red[0];
}

// ---------------- fused stage 1 + stage 2 (depthwise conv) — R15 proven ------
__global__ __launch_bounds__(256) void k_stage12(
    const float* __restrict__ d, const float* __restrict__ cd,
    const float* __restrict__ s, const float* __restrict__ cs,
    const float* __restrict__ w_s_from_d, const float* __restrict__ w_prop,
    const float* __restrict__ sw, const float* __restrict__ sums,
    ushort_t* __restrict__ XP, ushort_t* __restrict__ YP)
{
    __shared__ float2 uv_[4][TLY][TLX];   // 19,584 B (u=.x, v=.y)
    __shared__ float swl[4][9];

    int tid = threadIdx.x;
    int blk = blockIdx.x;
    constexpr int TX = W_ / TILEW, TY = H_ / TILEH;   // 6 x 12
    int tx0 = blk % TX; blk /= TX;
    int ty0 = blk % TY; blk /= TY;
    int c = blk % C_;
    int b = blk / C_;
    int h0 = ty0 * TILEH, w0 = tx0 * TILEW;

    const float* dbc  = d  + (size_t)(b * C_ + c) * NPIX;
    const float* cdbc = cd + (size_t)(b * C_ + c) * NPIX;

    if (tid < 36) swl[tid / 9][tid % 9] = sw[(c * 4 + tid / 9) * 9 + tid % 9];

    float w0s = w_s_from_d[0];
    float wp  = w_prop[c];
    float inv_wp1 = 1.f / (wp + 1.f);
    float inv_sw  = 1.f / (sums[0] + EPSV);
    float b1 = wp * inv_wp1;

    // fill: stage 1 on the halo-1 grid (18x34); only direction 0 survives the
    // reference's argmax over identical stacked copies.
    for (int i = tid; i < TLY * TLX; i += 256) {
        int y = i / TLX, x = i - y * TLX;
        int gh = h0 - 1 + y, gw = w0 - 1 + x;
        if ((unsigned)gh < (unsigned)H_ && (unsigned)gw < (unsigned)W_) {
            float mn = 0.f, cmn = 0.f, mx = 0.f, cmx = 0.f;
            if (gh >= 1 && gw >= 1) {
                size_t q = (size_t)(gh - 1) * W_ + (gw - 1);
                mn = dbc[q]; cmn = cdbc[q];
            }
            if (gh < H_ - 1 && gw < W_ - 1) {
                size_t q = (size_t)(gh + 1) * W_ + (gw + 1);
                mx = dbc[q]; cmx = cdbc[q];
            }
            float r = __fdividef(mn, mx + EPSV);
            r = fminf(fmaxf(r, 0.f), 1.f);
            float sfd = r * fmaf(w0s, r, 1.f - w0s);
            float cfd = cmn * cmx;
            float a1 = cfd * sfd * inv_wp1;
            float c1 = cfd * inv_wp1;
            size_t gbase = (size_t)((b * C_ + c) * 4) * NPIX + (size_t)gh * W_ + gw;
            #pragma unroll
            for (int k = 0; k < 4; ++k) {
                float s_v  = s[gbase + (size_t)k * NPIX];
                float cs_v = cs[gbase + (size_t)k * NPIX];
                float t = b1 * cs_v;
                uv_[k][y][x] = make_float2(fmaf(t, s_v, a1), t + c1);
            }
        } else {
            #pragma unroll
            for (int k = 0; k < 4; ++k) uv_[k][y][x] = make_float2(0.f, 0.f);
        }
    }
    __syncthreads();

    // conv: per-pixel, one b64 read per tap; thread covers 2 pixels
    #pragma unroll
    for (int p = 0; p < 2; ++p) {
        int i = p * 256 + tid;
        int ty = i >> 5, tx = i & 31;
        s16x8 kx, ky;
        #pragma unroll
        for (int k = 0; k < 4; ++k) {
            float nom = 0.f, den = 0.f;
            #pragma unroll
            for (int dy = 0; dy < 3; ++dy)
                #pragma unroll
                for (int dx = 0; dx < 3; ++dx) {
                    float2 P = uv_[k][ty + dy][tx + dx];
                    float wgt = swl[k][dy * 3 + dx];
                    nom = fmaf(wgt, P.x, nom);
                    den = fmaf(wgt, P.y, den);
                }
            float xv = nom * inv_sw;
            float yv = den * inv_sw;
            ushort_t hx = f2bu(xv);
            ushort_t hy = f2bu(yv);
            kx[k]     = (short)hx;
            kx[4 + k] = (short)f2bu(xv - bu2f(hx));
            ky[k]     = (short)hy;
            ky[4 + k] = (short)f2bu(yv - bu2f(hy));
        }
        int pb = (h0 + ty) * (W_ / 32) + (w0 >> 5);
        size_t base = ((size_t)(b * PB + pb) * 64 + c) * 256 + (size_t)tx * 8;
        *(s16x8*)(XP + base) = kx;
        *(s16x8*)(YP + base) = ky;
    }
}

// ---------------- stage 3: persistent double-buffered split-bf16 MFMA GEMM ---
// 512 blocks x 512 threads; each block owns 9 tiles (16 pix x 256 o).
// Two 32 KB LDS panels ping-pong: tile i+1's 4 stage-ops issue mid-compute of
// tile i. Counted vmcnt(16) at tile top (epilogue stores may fly; in-order
// retirement guarantees the older stages retired). 2 barriers/tile.
// Epilogue: direct 64B-contiguous stores from acc (no LDS -> no WAR).
__global__ __launch_bounds__(512) void k_stage3(
    const ushort_t* __restrict__ XP, const ushort_t* __restrict__ YP,
    const ushort_t* __restrict__ cwH, const ushort_t* __restrict__ cwL,
    const float* __restrict__ sums, float* __restrict__ out)
{
    __shared__ ushort_t stg[2 * 16384];   // 64 KiB: two panels of 32 KB

    int tid  = threadIdx.x;
    int wave = tid >> 6, lane = tid & 63;
    int l15 = lane & 15, l4 = lane >> 4;
    int bid = blockIdx.x;
    int o0 = wave * 32;

    // staging map (R12-proven): thread covers (p = chunk parity, sel = X/Y,
    // gl = g-local, pl = pixel); round r strides 4096 ushorts in both src+dst.
    int p_   = tid >> 8;
    int tidc = tid & 255;
    int sel  = tidc >> 7;
    int gl   = (tidc >> 4) & 7;
    int pl   = tidc & 15;
    const ushort_t* gbaseT = (sel ? YP : XP) + p_ * 2048 + gl * 256 + pl * 8;
    float inv_scw = 1.f / (sums[1] + EPSV);

    f32x4 accn[2], accd[2];
    s16x8 rx[2], ry[2];
    s16x8 rAh[2][2], rAl[2][2];

#define MFMA __builtin_amdgcn_mfma_f32_16x16x32_bf16

#define STAGE4(PAN, TB) do {                                                      \
    const ushort_t* gsrc_ = gbaseT + (TB);                                        \
    ushort_t* ldst_ = (PAN) + tid * 8;                                            \
    _Pragma("unroll")                                                             \
    for (int r_ = 0; r_ < 4; ++r_)                                                \
        async_ld16(gsrc_ + r_ * 4096, ldst_ + r_ * 4096);                         \
    } while (0)

#define LOADA(AB, KS) do {                                                        \
    _Pragma("unroll")                                                             \
    for (int m = 0; m < 2; ++m) {                                                 \
        size_t ro = (size_t)(o0 + m * 16 + l15) * C4 + (KS) * 32 + l4 * 8;        \
        rAh[AB][m] = *(const s16x8*)(cwH + ro);                                   \
        rAl[AB][m] = *(const s16x8*)(cwL + ro);                                   \
    } } while (0)

#define LOADB(PAN, KS) do {                                                       \
    const ushort_t* bp = (PAN) + (KS) * 2048;                                     \
    _Pragma("unroll")                                                             \
    for (int gg = 0; gg < 2; ++gg) {                                              \
        int o_ = (l4 * 2 + gg) * 128 + l15 * 8;                                   \
        rx[gg] = *(const s16x8*)(bp + o_);                                        \
        ry[gg] = *(const s16x8*)(bp + 1024 + o_);                                 \
    } } while (0)

#define COMPUTE(AB) do {                                                          \
    s16x8 bxh = __builtin_shufflevector(rx[0], rx[1], 0,1,2,3, 8,9,10,11);        \
    s16x8 bxl = __builtin_shufflevector(rx[0], rx[1], 4,5,6,7, 12,13,14,15);      \
    s16x8 byh = __builtin_shufflevector(ry[0], ry[1], 0,1,2,3, 8,9,10,11);        \
    s16x8 byl = __builtin_shufflevector(ry[0], ry[1], 4,5,6,7, 12,13,14,15);      \
    _Pragma("unroll")                                                             \
    for (int m = 0; m < 2; ++m) {                                                 \
        accn[m] = MFMA(rAh[AB][m], bxh, accn[m], 0, 0, 0);                        \
        accn[m] = MFMA(rAh[AB][m], bxl, accn[m], 0, 0, 0);                        \
        accn[m] = MFMA(rAl[AB][m], bxh, accn[m], 0, 0, 0);                        \
        accd[m] = MFMA(rAh[AB][m], byh, accd[m], 0, 0, 0);                        \
        accd[m] = MFMA(rAh[AB][m], byl, accd[m], 0, 0, 0);                        \
        accd[m] = MFMA(rAl[AB][m], byh, accd[m], 0, 0, 0);                        \
    } } while (0)

    // tile-base helper (ushort offset into XP/YP): t -> (b,pb32,ph)
    auto tilebase = [&](int t) -> size_t {
        int b = (t >= PB16) ? 1 : 0;
        int pbl = t - b * PB16;
        return (size_t)(b * PB + (pbl >> 1)) * 16384 + (size_t)(pbl & 1) * 128;
    };

    // prologue: stage tile 0 into panel 0
    STAGE4(stg, tilebase(bid));
    __builtin_amdgcn_sched_barrier(0);

    #pragma unroll 1
    for (int i = 0; i < 9; ++i) {
        int t  = bid + i * NBLK3;
        int cur = i & 1;
        ushort_t* pan = stg + cur * 16384;
        ushort_t* nxt = stg + (cur ^ 1) * 16384;

        __builtin_amdgcn_s_barrier();            // WAR: prev readers of `nxt` done
        if (i == 0) { asm volatile("s_waitcnt vmcnt(0)" ::: "memory"); }
        else        { asm volatile("s_waitcnt vmcnt(16)" ::: "memory"); }
        __builtin_amdgcn_s_barrier();            // all waves' panel stages landed
        __builtin_amdgcn_sched_barrier(0);

        accn[0] = f32x4{0.f, 0.f, 0.f, 0.f}; accn[1] = f32x4{0.f, 0.f, 0.f, 0.f};
        accd[0] = f32x4{0.f, 0.f, 0.f, 0.f}; accd[1] = f32x4{0.f, 0.f, 0.f, 0.f};

        LOADA(0, 0);
        LOADA(1, 1); LOADB(pan, 0); COMPUTE(0);
        LOADA(0, 2); LOADB(pan, 1); COMPUTE(1);
        LOADA(1, 3); LOADB(pan, 2); COMPUTE(0);
        LOADA(0, 4); LOADB(pan, 3); COMPUTE(1);

        if (i != 8) {                            // stage next tile mid-compute
            STAGE4(nxt, tilebase(t + NBLK3));
            __builtin_amdgcn_sched_barrier(0);
        }

        LOADA(1, 5); LOADB(pan, 4); COMPUTE(0);
        LOADA(0, 6); LOADB(pan, 5); COMPUTE(1);
        LOADA(1, 7); LOADB(pan, 6); COMPUTE(0);
        LOADB(pan, 7); COMPUTE(1);

        // epilogue: direct stores (16 per lane, 64B-contiguous per o-row)
        {
            int b = (t >= PB16) ? 1 : 0;
            int pbl = t - b * PB16;
            size_t gb = (size_t)b * C4 * NPIX + (size_t)pbl * 16 + l15;
            #pragma unroll
            for (int m = 0; m < 2; ++m)
                #pragma unroll
                for (int r = 0; r < 4; ++r) {
                    int o = o0 + m * 16 + l4 * 4 + r;
                    size_t oidx = gb + (size_t)o * NPIX;
                    float nv = accn[m][r], dv = accd[m][r];
                    out[oidx]      = nv / (dv + EPSV);
                    out[NT + oidx] = dv * inv_scw;
                }
        }
    }

#undef COMPUTE
#undef LOADB
#undef LOADA
#undef STAGE4
#undef MFMA
}

} // namespace

extern "C" void kernel_launch(void* const* d_in, const int* in_sizes, int n_in,
                              void* d_out, int out_size, void* d_ws, size_t ws_size,
                              hipStream_t stream) {
    const float* d    = (const float*)d_in[0];
    const float* cd   = (const float*)d_in[1];
    const float* s    = (const float*)d_in[2];
    const float* cs   = (const float*)d_in[3];
    const float* w_s  = (const float*)d_in[4];
    const float* wprp = (const float*)d_in[5];
    const float* cw   = (const float*)d_in[6];
    const float* sw   = (const float*)d_in[7];
    float* out = (float*)d_out;

    ushort_t* XP  = (ushort_t*)d_ws;
    ushort_t* YP  = XP + 2 * NT;
    ushort_t* cwH = YP + 2 * NT;
    ushort_t* cwL = cwH + C4 * C4;
    float* sums   = (float*)(cwL + C4 * C4);
    float* partial = sums + 2;

    k_prep<<<C4, 256, 0, stream>>>(cw, cwH, cwL, partial);
    k_sums2<<<1, 256, 0, stream>>>(sw, partial, sums);
    k_stage12<<<dim3(B_ * C_ * (H_ / TILEH) * (W_ / TILEW)), 256, 0, stream>>>(
        d, cd, s, cs, w_s, wprp, sw, sums, XP, YP);
    k_stage3<<<dim3(NBLK3), 512, 0, stream>>>(XP, YP, cwH, cwL, sums, out);
}

// Round 17
// 251.505 us; speedup vs baseline: 1.2000x; 1.2000x over previous
//
#include <hip/hip_runtime.h>

namespace {

typedef unsigned short ushort_t;
typedef short s16x8 __attribute__((ext_vector_type(8)));
typedef float f32x4 __attribute__((ext_vector_type(4)));

constexpr int B_ = 2, C_ = 64, H_ = 192, W_ = 192;
constexpr int C4 = 256;
constexpr int NPIX = H_ * W_;                       // 36864
constexpr size_t NT = (size_t)B_ * C4 * NPIX;       // 18,874,368
constexpr int PB = NPIX / 32;                       // 1152 32-pixel blocks per batch
constexpr float EPSV = 1e-20f;
constexpr int CHUNK = 2048;                         // ushorts per tensor per k-chunk

constexpr int TILEW = 32, TILEH = 16;
constexpr int TLX = TILEW + 2;   // 34
constexpr int TLY = TILEH + 2;   // 18

__device__ __forceinline__ ushort_t f2bu(float x) {
    union { float f; unsigned u; } v; v.f = x;
    unsigned r = v.u + 0x7fffu + ((v.u >> 16) & 1u);   // RNE to bf16
    return (ushort_t)(r >> 16);
}
__device__ __forceinline__ float bu2f(ushort_t h) {
    union { unsigned u; float f; } v; v.u = ((unsigned)h) << 16;
    return v.f;
}

__device__ __forceinline__ void async_ld16(const ushort_t* g, ushort_t* l) {
    __builtin_amdgcn_global_load_lds(
        (const __attribute__((address_space(1))) unsigned int*)g,
        (__attribute__((address_space(3))) unsigned int*)l, 16, 0, 0);
}

// ---------------- cw -> split bf16 hi/lo + per-block cw partial sums ----------
__global__ __launch_bounds__(256) void k_prep(const float* __restrict__ cw,
                                              ushort_t* __restrict__ cwH,
                                              ushort_t* __restrict__ cwL,
                                              float* __restrict__ partial) {
    __shared__ float red[256];
    int tid = threadIdx.x;
    int i = blockIdx.x * 256 + tid;   // grid 256 -> 65536
    float w = cw[i];
    ushort_t h = f2bu(w);
    cwH[i] = h;
    cwL[i] = f2bu(w - bu2f(h));
    red[tid] = w; __syncthreads();
    for (int s2 = 128; s2 > 0; s2 >>= 1) { if (tid < s2) red[tid] += red[tid + s2]; __syncthreads(); }
    if (tid == 0) partial[blockIdx.x] = red[0];
}

// ---------------- tiny final reduction: sw sum + cw partials ----------------
__global__ __launch_bounds__(256) void k_sums2(const float* __restrict__ sw,
                                               const float* __restrict__ partial,
                                               float* __restrict__ sums) {
    __shared__ float red[256];
    int tid = threadIdx.x;
    float a = 0.f;
    for (int i = tid; i < C4 * 9; i += 256) a += sw[i];
    red[tid] = a; __syncthreads();
    for (int s2 = 128; s2 > 0; s2 >>= 1) { if (tid < s2) red[tid] += red[tid + s2]; __syncthreads(); }
    if (tid == 0) sums[0] = red[0];
    __syncthreads();
    red[tid] = partial[tid]; __syncthreads();
    for (int s2 = 128; s2 > 0; s2 >>= 1) { if (tid < s2) red[tid] += red[tid + s2]; __syncthreads(); }
    if (tid == 0) sums[1] = red[0];
}

// ---------------- fused stage 1 + stage 2 (depthwise conv) — R15 proven ------
// 32x16 tile, 19.58 KB LDS -> 8 blocks/CU, ONE barrier, float2-interleaved u/v.
// Divisions cancel: U = cs_prop*s_prop = (wp*cs*s + cfd*sfd)/(wp+1),
// X = cs_spatial*s_spatial = conv(U)/sum_sw (den/(den+1e-20) == 1).
// Emits XP/YP packed split-bf16: element (b, pb, g, pix32, j) at
// ((b*PB+pb)*64 + g)*256 + pix*8 + j ; j = [hi of k=0..3 | lo of k=0..3].
__global__ __launch_bounds__(256) void k_stage12(
    const float* __restrict__ d, const float* __restrict__ cd,
    const float* __restrict__ s, const float* __restrict__ cs,
    const float* __restrict__ w_s_from_d, const float* __restrict__ w_prop,
    const float* __restrict__ sw, const float* __restrict__ sums,
    ushort_t* __restrict__ XP, ushort_t* __restrict__ YP)
{
    __shared__ float2 uv_[4][TLY][TLX];   // 19,584 B (u=.x, v=.y)
    __shared__ float swl[4][9];

    int tid = threadIdx.x;
    int blk = blockIdx.x;
    constexpr int TX = W_ / TILEW, TY = H_ / TILEH;   // 6 x 12
    int tx0 = blk % TX; blk /= TX;
    int ty0 = blk % TY; blk /= TY;
    int c = blk % C_;
    int b = blk / C_;
    int h0 = ty0 * TILEH, w0 = tx0 * TILEW;

    const float* dbc  = d  + (size_t)(b * C_ + c) * NPIX;
    const float* cdbc = cd + (size_t)(b * C_ + c) * NPIX;

    if (tid < 36) swl[tid / 9][tid % 9] = sw[(c * 4 + tid / 9) * 9 + tid % 9];

    float w0s = w_s_from_d[0];
    float wp  = w_prop[c];
    float inv_wp1 = 1.f / (wp + 1.f);
    float inv_sw  = 1.f / (sums[0] + EPSV);
    float b1 = wp * inv_wp1;

    // fill: stage 1 on the halo-1 grid (18x34); only direction 0 survives the
    // reference's argmax over identical stacked copies.
    for (int i = tid; i < TLY * TLX; i += 256) {
        int y = i / TLX, x = i - y * TLX;
        int gh = h0 - 1 + y, gw = w0 - 1 + x;
        if ((unsigned)gh < (unsigned)H_ && (unsigned)gw < (unsigned)W_) {
            float mn = 0.f, cmn = 0.f, mx = 0.f, cmx = 0.f;
            if (gh >= 1 && gw >= 1) {
                size_t q = (size_t)(gh - 1) * W_ + (gw - 1);
                mn = dbc[q]; cmn = cdbc[q];
            }
            if (gh < H_ - 1 && gw < W_ - 1) {
                size_t q = (size_t)(gh + 1) * W_ + (gw + 1);
                mx = dbc[q]; cmx = cdbc[q];
            }
            float r = __fdividef(mn, mx + EPSV);
            r = fminf(fmaxf(r, 0.f), 1.f);
            float sfd = r * fmaf(w0s, r, 1.f - w0s);
            float cfd = cmn * cmx;
            float a1 = cfd * sfd * inv_wp1;
            float c1 = cfd * inv_wp1;
            size_t gbase = (size_t)((b * C_ + c) * 4) * NPIX + (size_t)gh * W_ + gw;
            #pragma unroll
            for (int k = 0; k < 4; ++k) {
                float s_v  = s[gbase + (size_t)k * NPIX];
                float cs_v = cs[gbase + (size_t)k * NPIX];
                float t = b1 * cs_v;
                uv_[k][y][x] = make_float2(fmaf(t, s_v, a1), t + c1);
            }
        } else {
            #pragma unroll
            for (int k = 0; k < 4; ++k) uv_[k][y][x] = make_float2(0.f, 0.f);
        }
    }
    __syncthreads();

    // conv: per-pixel, one b64 read per tap; thread covers 2 pixels
    #pragma unroll
    for (int p = 0; p < 2; ++p) {
        int i = p * 256 + tid;
        int ty = i >> 5, tx = i & 31;
        s16x8 kx, ky;
        #pragma unroll
        for (int k = 0; k < 4; ++k) {
            float nom = 0.f, den = 0.f;
            #pragma unroll
            for (int dy = 0; dy < 3; ++dy)
                #pragma unroll
                for (int dx = 0; dx < 3; ++dx) {
                    float2 P = uv_[k][ty + dy][tx + dx];
                    float wgt = swl[k][dy * 3 + dx];
                    nom = fmaf(wgt, P.x, nom);
                    den = fmaf(wgt, P.y, den);
                }
            float xv = nom * inv_sw;
            float yv = den * inv_sw;
            ushort_t hx = f2bu(xv);
            ushort_t hy = f2bu(yv);
            kx[k]     = (short)hx;
            kx[4 + k] = (short)f2bu(xv - bu2f(hx));
            ky[k]     = (short)hy;
            ky[4 + k] = (short)f2bu(yv - bu2f(hy));
        }
        int pb = (h0 + ty) * (W_ / 32) + (w0 >> 5);
        size_t base = ((size_t)(b * PB + pb) * 64 + c) * 256 + (size_t)tx * 8;
        *(s16x8*)(XP + base) = kx;
        *(s16x8*)(YP + base) = ky;
    }
}

// ---------------- stage 3: split-bf16 MFMA GEMM, monolithic LDS stage --------
// R15-proven: 512 threads (8 waves), tile 256 o x 32 pix, whole 64 KB B-panel
// staged via global_load_lds, 2-barrier counted-vmcnt schedule. Epilogue now
// stores DIRECTLY from acc (R16-verified exact-write 64B-segment pattern) —
// no LDS transpose, no tail barriers.
__global__ __launch_bounds__(512, 4) void k_stage3(
    const ushort_t* __restrict__ XP, const ushort_t* __restrict__ YP,
    const ushort_t* __restrict__ cwH, const ushort_t* __restrict__ cwL,
    const float* __restrict__ sums, float* __restrict__ out)
{
    __shared__ ushort_t stg[8 * 2 * CHUNK];   // 64 KiB: 8 chunks x [X 4KB | Y 4KB]

    int tid  = threadIdx.x;
    int wave = tid >> 6, lane = tid & 63;
    int l15 = lane & 15, l4 = lane >> 4;
    int pb = blockIdx.x;
    int b  = blockIdx.y;
    int o0 = wave * 32;

    size_t xbase = (size_t)(b * PB + pb) * 16384;   // ushorts: 64 g * 256
    const ushort_t* gsrc = ((wave & 4) ? YP : XP) + xbase
                         + (size_t)(wave & 3) * 512 + (size_t)lane * 8;
    ushort_t* lbase = stg + ((wave & 4) ? CHUNK : 0) + (wave & 3) * 512;

    f32x4 accn[2][2] = {};
    f32x4 accd[2][2] = {};
    s16x8 rx[2][2], ry[2][2];
    s16x8 rAh[2][2], rAl[2][2];

#define MFMA __builtin_amdgcn_mfma_f32_16x16x32_bf16

#define STAGE(KS) async_ld16(gsrc + (size_t)(KS) * 2048, lbase + (KS) * (2 * CHUNK))

#define LOADA(AB, KS) do {                                                        \
    _Pragma("unroll")                                                             \
    for (int m = 0; m < 2; ++m) {                                                 \
        size_t ro = (size_t)(o0 + m * 16 + l15) * C4 + (KS) * 32 + l4 * 8;        \
        rAh[AB][m] = *(const s16x8*)(cwH + ro);                                   \
        rAl[AB][m] = *(const s16x8*)(cwL + ro);                                   \
    } } while (0)

#define LOADB(KS) do {                                                            \
    const ushort_t* bp = stg + (KS) * (2 * CHUNK);                                \
    _Pragma("unroll")                                                             \
    for (int n = 0; n < 2; ++n)                                                   \
        _Pragma("unroll")                                                         \
        for (int gg = 0; gg < 2; ++gg) {                                          \
            int o_ = (l4 * 2 + gg) * 256 + (n * 16 + l15) * 8;                    \
            rx[n][gg] = *(const s16x8*)(bp + o_);                                 \
            ry[n][gg] = *(const s16x8*)(bp + CHUNK + o_);                         \
        } } while (0)

#define COMPUTE(AB) do {                                                          \
    _Pragma("unroll")                                                             \
    for (int n = 0; n < 2; ++n) {                                                 \
        s16x8 bxh = __builtin_shufflevector(rx[n][0], rx[n][1], 0,1,2,3, 8,9,10,11);   \
        s16x8 bxl = __builtin_shufflevector(rx[n][0], rx[n][1], 4,5,6,7, 12,13,14,15); \
        s16x8 byh = __builtin_shufflevector(ry[n][0], ry[n][1], 0,1,2,3, 8,9,10,11);   \
        s16x8 byl = __builtin_shufflevector(ry[n][0], ry[n][1], 4,5,6,7, 12,13,14,15); \
        _Pragma("unroll")                                                         \
        for (int m = 0; m < 2; ++m) {                                             \
            accn[m][n] = MFMA(rAh[AB][m], bxh, accn[m][n], 0, 0, 0);              \
            accn[m][n] = MFMA(rAh[AB][m], bxl, accn[m][n], 0, 0, 0);              \
            accn[m][n] = MFMA(rAl[AB][m], bxh, accn[m][n], 0, 0, 0);              \
            accd[m][n] = MFMA(rAh[AB][m], byh, accd[m][n], 0, 0, 0);              \
            accd[m][n] = MFMA(rAh[AB][m], byl, accd[m][n], 0, 0, 0);              \
            accd[m][n] = MFMA(rAl[AB][m], byh, accd[m][n], 0, 0, 0);              \
        } } } while (0)

    // prologue: stage ALL 8 chunks (8 VMEM), then A0 (4 VMEM)
    STAGE(0); STAGE(1); STAGE(2); STAGE(3);
    STAGE(4); STAGE(5); STAGE(6); STAGE(7);
    __builtin_amdgcn_sched_barrier(0);
    LOADA(0, 0);
    __builtin_amdgcn_sched_barrier(0);

    // wait: own S0..S3 retired (12 issued, <=8 outstanding -> >=4 retired)
    asm volatile("s_waitcnt vmcnt(8)" ::: "memory");
    __builtin_amdgcn_s_barrier();
    __builtin_amdgcn_sched_barrier(0);

    LOADA(1, 1); LOADB(0); COMPUTE(0);
    LOADA(0, 2); LOADB(1); COMPUTE(1);
    LOADA(1, 3); LOADB(2); COMPUTE(0);
    LOADA(0, 4); LOADB(3); COMPUTE(1);

    // wait: own S0..S7 retired (28 issued by now, <=20 outstanding -> >=8 retired)
    asm volatile("s_waitcnt vmcnt(20)" ::: "memory");
    __builtin_amdgcn_s_barrier();
    __builtin_amdgcn_sched_barrier(0);

    LOADA(1, 5); LOADB(4); COMPUTE(0);
    LOADA(0, 6); LOADB(5); COMPUTE(1);
    LOADA(1, 7); LOADB(6); COMPUTE(0);
    LOADB(7); COMPUTE(1);

#undef COMPUTE
#undef LOADB
#undef LOADA
#undef STAGE
#undef MFMA

    // -------- epilogue: direct stores from acc (R16-verified exact-write) ----
    // Per instruction: 16 lanes x 4B = 64B contiguous per o-row; no LDS,
    // no tail barriers -> block retires as soon as stores issue.
    float inv_scw = 1.f / (sums[1] + EPSV);
    size_t gb = (size_t)b * C4 * NPIX + (size_t)pb * 32;
    #pragma unroll
    for (int m = 0; m < 2; ++m)
        #pragma unroll
        for (int n = 0; n < 2; ++n)
            #pragma unroll
            for (int r = 0; r < 4; ++r) {
                int o   = o0 + m * 16 + l4 * 4 + r;
                size_t oidx = gb + (size_t)o * NPIX + n * 16 + l15;
                float nv = accn[m][n][r], dv = accd[m][n][r];
                out[oidx]      = nv / (dv + EPSV);
                out[NT + oidx] = dv * inv_scw;
            }
}

} // namespace

extern "C" void kernel_launch(void* const* d_in, const int* in_sizes, int n_in,
                              void* d_out, int out_size, void* d_ws, size_t ws_size,
                              hipStream_t stream) {
    const float* d    = (const float*)d_in[0];
    const float* cd   = (const float*)d_in[1];
    const float* s    = (const float*)d_in[2];
    const float* cs   = (const float*)d_in[3];
    const float* w_s  = (const float*)d_in[4];
    const float* wprp = (const float*)d_in[5];
    const float* cw   = (const float*)d_in[6];
    const float* sw   = (const float*)d_in[7];
    float* out = (float*)d_out;

    ushort_t* XP  = (ushort_t*)d_ws;
    ushort_t* YP  = XP + 2 * NT;
    ushort_t* cwH = YP + 2 * NT;
    ushort_t* cwL = cwH + C4 * C4;
    float* sums   = (float*)(cwL + C4 * C4);
    float* partial = sums + 2;

    k_prep<<<C4, 256, 0, stream>>>(cw, cwH, cwL, partial);
    k_sums2<<<1, 256, 0, stream>>>(sw, partial, sums);
    // 6 x 12 tiles per (b,c) = 9216 blocks
    k_stage12<<<dim3(B_ * C_ * (H_ / TILEH) * (W_ / TILEW)), 256, 0, stream>>>(
        d, cd, s, cs, w_s, wprp, sw, sums, XP, YP);
    k_stage3<<<dim3(PB, B_), 512, 0, stream>>>(XP, YP, cwH, cwL, sums, out);
}

// Round 18
// 242.668 us; speedup vs baseline: 1.2437x; 1.0364x over previous
//
#include <hip/hip_runtime.h>

namespace {

typedef unsigned short ushort_t;
typedef short s16x8 __attribute__((ext_vector_type(8)));
typedef float f32x4 __attribute__((ext_vector_type(4)));

constexpr int B_ = 2, C_ = 64, H_ = 192, W_ = 192;
constexpr int C4 = 256;
constexpr int NPIX = H_ * W_;                       // 36864
constexpr size_t NT = (size_t)B_ * C4 * NPIX;       // 18,874,368
constexpr int PB = NPIX / 32;                       // 1152 32-pixel blocks per batch
constexpr float EPSV = 1e-20f;
constexpr int CHUNK = 2048;                         // ushorts per tensor per k-chunk

constexpr int TILEW = 32, TILEH = 16;
constexpr int TLX = TILEW + 2;   // 34
constexpr int TLY = TILEH + 2;   // 18

__device__ __forceinline__ ushort_t f2bu(float x) {
    union { float f; unsigned u; } v; v.f = x;
    unsigned r = v.u + 0x7fffu + ((v.u >> 16) & 1u);   // RNE to bf16
    return (ushort_t)(r >> 16);
}
__device__ __forceinline__ float bu2f(ushort_t h) {
    union { unsigned u; float f; } v; v.u = ((unsigned)h) << 16;
    return v.f;
}

__device__ __forceinline__ void async_ld16(const ushort_t* g, ushort_t* l) {
    __builtin_amdgcn_global_load_lds(
        (const __attribute__((address_space(1))) unsigned int*)g,
        (__attribute__((address_space(3))) unsigned int*)l, 16, 0, 0);
}

// ---------------- cw -> split bf16 hi/lo + per-block cw partial sums ----------
__global__ __launch_bounds__(256) void k_prep(const float* __restrict__ cw,
                                              ushort_t* __restrict__ cwH,
                                              ushort_t* __restrict__ cwL,
                                              float* __restrict__ partial) {
    __shared__ float red[256];
    int tid = threadIdx.x;
    int i = blockIdx.x * 256 + tid;   // grid 256 -> 65536
    float w = cw[i];
    ushort_t h = f2bu(w);
    cwH[i] = h;
    cwL[i] = f2bu(w - bu2f(h));
    red[tid] = w; __syncthreads();
    for (int s2 = 128; s2 > 0; s2 >>= 1) { if (tid < s2) red[tid] += red[tid + s2]; __syncthreads(); }
    if (tid == 0) partial[blockIdx.x] = red[0];
}

// ---------------- tiny final reduction: sw sum + cw partials ----------------
__global__ __launch_bounds__(256) void k_sums2(const float* __restrict__ sw,
                                               const float* __restrict__ partial,
                                               float* __restrict__ sums) {
    __shared__ float red[256];
    int tid = threadIdx.x;
    float a = 0.f;
    for (int i = tid; i < C4 * 9; i += 256) a += sw[i];
    red[tid] = a; __syncthreads();
    for (int s2 = 128; s2 > 0; s2 >>= 1) { if (tid < s2) red[tid] += red[tid + s2]; __syncthreads(); }
    if (tid == 0) sums[0] = red[0];
    __syncthreads();
    red[tid] = partial[tid]; __syncthreads();
    for (int s2 = 128; s2 > 0; s2 >>= 1) { if (tid < s2) red[tid] += red[tid + s2]; __syncthreads(); }
    if (tid == 0) sums[1] = red[0];
}

// ---------------- fused stage 1 + stage 2 (depthwise conv) — R15 proven ------
// 32x16 tile, 19.58 KB LDS -> 8 blocks/CU, ONE barrier, float2-interleaved u/v.
__global__ __launch_bounds__(256) void k_stage12(
    const float* __restrict__ d, const float* __restrict__ cd,
    const float* __restrict__ s, const float* __restrict__ cs,
    const float* __restrict__ w_s_from_d, const float* __restrict__ w_prop,
    const float* __restrict__ sw, const float* __restrict__ sums,
    ushort_t* __restrict__ XP, ushort_t* __restrict__ YP)
{
    __shared__ float2 uv_[4][TLY][TLX];   // 19,584 B (u=.x, v=.y)
    __shared__ float swl[4][9];

    int tid = threadIdx.x;
    int blk = blockIdx.x;
    constexpr int TX = W_ / TILEW, TY = H_ / TILEH;   // 6 x 12
    int tx0 = blk % TX; blk /= TX;
    int ty0 = blk % TY; blk /= TY;
    int c = blk % C_;
    int b = blk / C_;
    int h0 = ty0 * TILEH, w0 = tx0 * TILEW;

    const float* dbc  = d  + (size_t)(b * C_ + c) * NPIX;
    const float* cdbc = cd + (size_t)(b * C_ + c) * NPIX;

    if (tid < 36) swl[tid / 9][tid % 9] = sw[(c * 4 + tid / 9) * 9 + tid % 9];

    float w0s = w_s_from_d[0];
    float wp  = w_prop[c];
    float inv_wp1 = 1.f / (wp + 1.f);
    float inv_sw  = 1.f / (sums[0] + EPSV);
    float b1 = wp * inv_wp1;

    // fill: stage 1 on the halo-1 grid (18x34); only direction 0 survives the
    // reference's argmax over identical stacked copies.
    for (int i = tid; i < TLY * TLX; i += 256) {
        int y = i / TLX, x = i - y * TLX;
        int gh = h0 - 1 + y, gw = w0 - 1 + x;
        if ((unsigned)gh < (unsigned)H_ && (unsigned)gw < (unsigned)W_) {
            float mn = 0.f, cmn = 0.f, mx = 0.f, cmx = 0.f;
            if (gh >= 1 && gw >= 1) {
                size_t q = (size_t)(gh - 1) * W_ + (gw - 1);
                mn = dbc[q]; cmn = cdbc[q];
            }
            if (gh < H_ - 1 && gw < W_ - 1) {
                size_t q = (size_t)(gh + 1) * W_ + (gw + 1);
                mx = dbc[q]; cmx = cdbc[q];
            }
            float r = __fdividef(mn, mx + EPSV);
            r = fminf(fmaxf(r, 0.f), 1.f);
            float sfd = r * fmaf(w0s, r, 1.f - w0s);
            float cfd = cmn * cmx;
            float a1 = cfd * sfd * inv_wp1;
            float c1 = cfd * inv_wp1;
            size_t gbase = (size_t)((b * C_ + c) * 4) * NPIX + (size_t)gh * W_ + gw;
            #pragma unroll
            for (int k = 0; k < 4; ++k) {
                float s_v  = s[gbase + (size_t)k * NPIX];
                float cs_v = cs[gbase + (size_t)k * NPIX];
                float t = b1 * cs_v;
                uv_[k][y][x] = make_float2(fmaf(t, s_v, a1), t + c1);
            }
        } else {
            #pragma unroll
            for (int k = 0; k < 4; ++k) uv_[k][y][x] = make_float2(0.f, 0.f);
        }
    }
    __syncthreads();

    // conv: per-pixel, one b64 read per tap; thread covers 2 pixels
    #pragma unroll
    for (int p = 0; p < 2; ++p) {
        int i = p * 256 + tid;
        int ty = i >> 5, tx = i & 31;
        s16x8 kx, ky;
        #pragma unroll
        for (int k = 0; k < 4; ++k) {
            float nom = 0.f, den = 0.f;
            #pragma unroll
            for (int dy = 0; dy < 3; ++dy)
                #pragma unroll
                for (int dx = 0; dx < 3; ++dx) {
                    float2 P = uv_[k][ty + dy][tx + dx];
                    float wgt = swl[k][dy * 3 + dx];
                    nom = fmaf(wgt, P.x, nom);
                    den = fmaf(wgt, P.y, den);
                }
            float xv = nom * inv_sw;
            float yv = den * inv_sw;
            ushort_t hx = f2bu(xv);
            ushort_t hy = f2bu(yv);
            kx[k]     = (short)hx;
            kx[4 + k] = (short)f2bu(xv - bu2f(hx));
            ky[k]     = (short)hy;
            ky[4 + k] = (short)f2bu(yv - bu2f(hy));
        }
        int pb = (h0 + ty) * (W_ / 32) + (w0 >> 5);
        size_t base = ((size_t)(b * PB + pb) * 64 + c) * 256 + (size_t)tx * 8;
        *(s16x8*)(XP + base) = kx;
        *(s16x8*)(YP + base) = ky;
    }
}

// ---------------- stage 3: split-bf16 MFMA GEMM, 6-chunk LDS + global tail ---
// R15 structure but panel = chunks 0-5 only (48 KB -> 3 blocks/CU); chunks 6-7
// B-fragments read directly from global (L3-warm), prefetched one chunk ahead.
// Counted waits: 10 issued -> vmcnt(6) retires S0-3; 26 issued -> vmcnt(20)
// retires S0-5. Transpose epilogue (R15/R17 A/B: full-line stores win).
__global__ __launch_bounds__(512, 6) void k_stage3(
    const ushort_t* __restrict__ XP, const ushort_t* __restrict__ YP,
    const ushort_t* __restrict__ cwH, const ushort_t* __restrict__ cwL,
    const float* __restrict__ sums, float* __restrict__ out)
{
    __shared__ ushort_t stg[6 * 2 * CHUNK];   // 48 KiB: chunks 0-5 x [X 4KB | Y 4KB]

    int tid  = threadIdx.x;
    int wave = tid >> 6, lane = tid & 63;
    int l15 = lane & 15, l4 = lane >> 4;
    int pb = blockIdx.x;
    int b  = blockIdx.y;
    int o0 = wave * 32;

    size_t xbase = (size_t)(b * PB + pb) * 16384;   // ushorts: 64 g * 256
    const ushort_t* gsrc = ((wave & 4) ? YP : XP) + xbase
                         + (size_t)(wave & 3) * 512 + (size_t)lane * 8;
    ushort_t* lbase = stg + ((wave & 4) ? CHUNK : 0) + (wave & 3) * 512;
    const ushort_t* gx = XP + xbase;
    const ushort_t* gy = YP + xbase;

    f32x4 accn[2][2] = {};
    f32x4 accd[2][2] = {};
    s16x8 rx[2][2], ry[2][2];
    s16x8 rgx[2][2], rgy[2][2];
    s16x8 rAh[2][2], rAl[2][2];

#define MFMA __builtin_amdgcn_mfma_f32_16x16x32_bf16

#define STAGE(KS) async_ld16(gsrc + (size_t)(KS) * 2048, lbase + (KS) * (2 * CHUNK))

#define LOADA(AB, KS) do {                                                        \
    _Pragma("unroll")                                                             \
    for (int m = 0; m < 2; ++m) {                                                 \
        size_t ro = (size_t)(o0 + m * 16 + l15) * C4 + (KS) * 32 + l4 * 8;        \
        rAh[AB][m] = *(const s16x8*)(cwH + ro);                                   \
        rAl[AB][m] = *(const s16x8*)(cwL + ro);                                   \
    } } while (0)

#define LOADB(KS) do {                                                            \
    const ushort_t* bp = stg + (KS) * (2 * CHUNK);                                \
    _Pragma("unroll")                                                             \
    for (int n = 0; n < 2; ++n)                                                   \
        _Pragma("unroll")                                                         \
        for (int gg = 0; gg < 2; ++gg) {                                          \
            int o_ = (l4 * 2 + gg) * 256 + (n * 16 + l15) * 8;                    \
            rx[n][gg] = *(const s16x8*)(bp + o_);                                 \
            ry[n][gg] = *(const s16x8*)(bp + CHUNK + o_);                         \
        } } while (0)

#define LOADBG(KS, RX, RY) do {                                                   \
    _Pragma("unroll")                                                             \
    for (int n = 0; n < 2; ++n)                                                   \
        _Pragma("unroll")                                                         \
        for (int gg = 0; gg < 2; ++gg) {                                          \
            int o_ = (KS) * 2048 + (l4 * 2 + gg) * 256 + (n * 16 + l15) * 8;      \
            RX[n][gg] = *(const s16x8*)(gx + o_);                                 \
            RY[n][gg] = *(const s16x8*)(gy + o_);                                 \
        } } while (0)

#define COMPUTE(AB, RX, RY) do {                                                  \
    _Pragma("unroll")                                                             \
    for (int n = 0; n < 2; ++n) {                                                 \
        s16x8 bxh = __builtin_shufflevector(RX[n][0], RX[n][1], 0,1,2,3, 8,9,10,11);   \
        s16x8 bxl = __builtin_shufflevector(RX[n][0], RX[n][1], 4,5,6,7, 12,13,14,15); \
        s16x8 byh = __builtin_shufflevector(RY[n][0], RY[n][1], 0,1,2,3, 8,9,10,11);   \
        s16x8 byl = __builtin_shufflevector(RY[n][0], RY[n][1], 4,5,6,7, 12,13,14,15); \
        _Pragma("unroll")                                                         \
        for (int m = 0; m < 2; ++m) {                                             \
            accn[m][n] = MFMA(rAh[AB][m], bxh, accn[m][n], 0, 0, 0);              \
            accn[m][n] = MFMA(rAh[AB][m], bxl, accn[m][n], 0, 0, 0);              \
            accn[m][n] = MFMA(rAl[AB][m], bxh, accn[m][n], 0, 0, 0);              \
            accd[m][n] = MFMA(rAh[AB][m], byh, accd[m][n], 0, 0, 0);              \
            accd[m][n] = MFMA(rAh[AB][m], byl, accd[m][n], 0, 0, 0);              \
            accd[m][n] = MFMA(rAl[AB][m], byh, accd[m][n], 0, 0, 0);              \
        } } } while (0)

    // prologue: stage chunks 0-5 (6 VMEM), then A0 (4 VMEM) -> 10 issued
    STAGE(0); STAGE(1); STAGE(2); STAGE(3); STAGE(4); STAGE(5);
    __builtin_amdgcn_sched_barrier(0);
    LOADA(0, 0);
    __builtin_amdgcn_sched_barrier(0);

    // S0..S3 retired (10 issued, <=6 outstanding -> >=4 retired)
    asm volatile("s_waitcnt vmcnt(6)" ::: "memory");
    __builtin_amdgcn_s_barrier();
    __builtin_amdgcn_sched_barrier(0);

    LOADA(1, 1); LOADB(0); COMPUTE(0, rx, ry);
    LOADA(0, 2); LOADB(1); COMPUTE(1, rx, ry);
    LOADA(1, 3); LOADB(2); COMPUTE(0, rx, ry);
    LOADA(0, 4); LOADB(3); COMPUTE(1, rx, ry);

    // 26 issued; S0..S5 retired (<=20 outstanding -> >=6 retired)
    asm volatile("s_waitcnt vmcnt(20)" ::: "memory");
    __builtin_amdgcn_s_barrier();
    __builtin_amdgcn_sched_barrier(0);

    LOADBG(6, rgx, rgy);                       // chunk-6 prefetch (L3-warm)
    LOADA(1, 5); LOADB(4); COMPUTE(0, rx, ry);
    LOADA(0, 6); LOADB(5); COMPUTE(1, rx, ry);
    LOADA(1, 7); LOADBG(7, rx, ry);            // chunk-7 flies under chunk-6 MFMAs
    COMPUTE(0, rgx, rgy);
    COMPUTE(1, rx, ry);

#undef COMPUTE
#undef LOADBG
#undef LOADB
#undef LOADA
#undef STAGE
#undef MFMA

    // -------- epilogue: LDS transpose -> full-line coalesced stores --------
    float* ts = reinterpret_cast<float*>(stg);   // 256 x 36 floats = 36,864 B
    float inv_scw = 1.f / (sums[1] + EPSV);
    __syncthreads();   // all LOADB consumers of stg finished

    #pragma unroll
    for (int pass2 = 0; pass2 < 2; ++pass2) {
        #pragma unroll
        for (int m = 0; m < 2; ++m)
            #pragma unroll
            for (int n = 0; n < 2; ++n)
                #pragma unroll
                for (int r = 0; r < 4; ++r) {
                    int o = o0 + m * 16 + l4 * 4 + r;
                    float nv = accn[m][n][r], dv = accd[m][n][r];
                    float val = pass2 ? dv * inv_scw : nv / (dv + EPSV);
                    ts[o * 36 + n * 16 + l15] = val;
                }
        __syncthreads();
        size_t gb = (pass2 ? NT : 0) + (size_t)b * C4 * NPIX + (size_t)pb * 32;
        int oo = tid >> 3, j = tid & 7;
        #pragma unroll
        for (int pass = 0; pass < 4; ++pass) {
            int o = pass * 64 + oo;
            f32x4 v = *(const f32x4*)&ts[o * 36 + j * 4];
            *(f32x4*)&out[gb + (size_t)o * NPIX + j * 4] = v;
        }
        if (pass2 == 0) __syncthreads();
    }
}

} // namespace

extern "C" void kernel_launch(void* const* d_in, const int* in_sizes, int n_in,
                              void* d_out, int out_size, void* d_ws, size_t ws_size,
                              hipStream_t stream) {
    const float* d    = (const float*)d_in[0];
    const float* cd   = (const float*)d_in[1];
    const float* s    = (const float*)d_in[2];
    const float* cs   = (const float*)d_in[3];
    const float* w_s  = (const float*)d_in[4];
    const float* wprp = (const float*)d_in[5];
    const float* cw   = (const float*)d_in[6];
    const float* sw   = (const float*)d_in[7];
    float* out = (float*)d_out;

    ushort_t* XP  = (ushort_t*)d_ws;
    ushort_t* YP  = XP + 2 * NT;
    ushort_t* cwH = YP + 2 * NT;
    ushort_t* cwL = cwH + C4 * C4;
    float* sums   = (float*)(cwL + C4 * C4);
    float* partial = sums + 2;

    k_prep<<<C4, 256, 0, stream>>>(cw, cwH, cwL, partial);
    k_sums2<<<1, 256, 0, stream>>>(sw, partial, sums);
    // 6 x 12 tiles per (b,c) = 9216 blocks
    k_stage12<<<dim3(B_ * C_ * (H_ / TILEH) * (W_ / TILEW)), 256, 0, stream>>>(
        d, cd, s, cs, w_s, wprp, sw, sums, XP, YP);
    k_stage3<<<dim3(PB, B_), 512, 0, stream>>>(XP, YP, cwH, cwL, sums, out);
}

// Round 19
// 215.038 us; speedup vs baseline: 1.4035x; 1.1285x over previous
//
#include <hip/hip_runtime.h>

namespace {

typedef unsigned short ushort_t;
typedef unsigned char u8;
typedef short s16x8 __attribute__((ext_vector_type(8)));
typedef float f32x4 __attribute__((ext_vector_type(4)));

constexpr int B_ = 2, C_ = 64, H_ = 192, W_ = 192;
constexpr int C4 = 256;
constexpr int NPIX = H_ * W_;                       // 36864
constexpr size_t NT = (size_t)B_ * C4 * NPIX;       // 18,874,368
constexpr int PB = NPIX / 32;                       // 1152 32-pixel blocks per batch
constexpr float EPSV = 1e-20f;
constexpr float QS = 16383.f;
constexpr float INVQS = 1.f / 16383.f;

constexpr int TILEW = 32, TILEH = 16;
constexpr int TLX = TILEW + 2;   // 34
constexpr int TLY = TILEH + 2;   // 18

__device__ __forceinline__ ushort_t f2bu(float x) {
    union { float f; unsigned u; } v; v.f = x;
    unsigned r = v.u + 0x7fffu + ((v.u >> 16) & 1u);   // RNE to bf16
    return (ushort_t)(r >> 16);
}
__device__ __forceinline__ float bu2f(ushort_t h) {
    union { unsigned u; float f; } v; v.u = ((unsigned)h) << 16;
    return v.f;
}

__device__ __forceinline__ void async_ld16(const u8* g, u8* l) {
    __builtin_amdgcn_global_load_lds(
        (const __attribute__((address_space(1))) unsigned int*)g,
        (__attribute__((address_space(3))) unsigned int*)l, 16, 0, 0);
}

// two bf16 (packed u32) from two bytes of w — exact for ints <= 255
__device__ __forceinline__ unsigned bfp(unsigned w, int b0, int b1) {
    float f0 = (float)((w >> (8 * b0)) & 0xFFu);
    float f1 = (float)((w >> (8 * b1)) & 0xFFu);
    return (__float_as_uint(f0) >> 16) | (__float_as_uint(f1) & 0xFFFF0000u);
}

// ---------------- cw -> split bf16 hi/lo + per-block cw partial sums ----------
__global__ __launch_bounds__(256) void k_prep(const float* __restrict__ cw,
                                              ushort_t* __restrict__ cwH,
                                              ushort_t* __restrict__ cwL,
                                              float* __restrict__ partial) {
    __shared__ float red[256];
    int tid = threadIdx.x;
    int i = blockIdx.x * 256 + tid;   // grid 256 -> 65536
    float w = cw[i];
    ushort_t h = f2bu(w);
    cwH[i] = h;
    cwL[i] = f2bu(w - bu2f(h));
    red[tid] = w; __syncthreads();
    for (int s2 = 128; s2 > 0; s2 >>= 1) { if (tid < s2) red[tid] += red[tid + s2]; __syncthreads(); }
    if (tid == 0) partial[blockIdx.x] = red[0];
}

// ---------------- tiny final reduction: sw sum + cw partials ----------------
__global__ __launch_bounds__(256) void k_sums2(const float* __restrict__ sw,
                                               const float* __restrict__ partial,
                                               float* __restrict__ sums) {
    __shared__ float red[256];
    int tid = threadIdx.x;
    float a = 0.f;
    for (int i = tid; i < C4 * 9; i += 256) a += sw[i];
    red[tid] = a; __syncthreads();
    for (int s2 = 128; s2 > 0; s2 >>= 1) { if (tid < s2) red[tid] += red[tid + s2]; __syncthreads(); }
    if (tid == 0) sums[0] = red[0];
    __syncthreads();
    red[tid] = partial[tid]; __syncthreads();
    for (int s2 = 128; s2 > 0; s2 >>= 1) { if (tid < s2) red[tid] += red[tid + s2]; __syncthreads(); }
    if (tid == 0) sums[1] = red[0];
}

// ---------------- fused stage 1 + stage 2 (depthwise conv) — R15 structure ---
// 32x16 tile, 19.58 KB LDS -> 8 blocks/CU, ONE barrier, float2-interleaved u/v.
// NEW: outputs quantized u8 fixed-point (q = rint(x*16383); H=q>>7, L=q&127).
// XP/YP layout (u8): tile (b,pb) at (b*PB+pb)*16384; per g: 256 B = 32 pix x
// {H0..H3, L0..L3}. 8 B per pixel -> uint2 stores.
__global__ __launch_bounds__(256) void k_stage12(
    const float* __restrict__ d, const float* __restrict__ cd,
    const float* __restrict__ s, const float* __restrict__ cs,
    const float* __restrict__ w_s_from_d, const float* __restrict__ w_prop,
    const float* __restrict__ sw, const float* __restrict__ sums,
    u8* __restrict__ XP, u8* __restrict__ YP)
{
    __shared__ float2 uv_[4][TLY][TLX];   // 19,584 B (u=.x, v=.y)
    __shared__ float swl[4][9];

    int tid = threadIdx.x;
    int blk = blockIdx.x;
    constexpr int TX = W_ / TILEW, TY = H_ / TILEH;   // 6 x 12
    int tx0 = blk % TX; blk /= TX;
    int ty0 = blk % TY; blk /= TY;
    int c = blk % C_;
    int b = blk / C_;
    int h0 = ty0 * TILEH, w0 = tx0 * TILEW;

    const float* dbc  = d  + (size_t)(b * C_ + c) * NPIX;
    const float* cdbc = cd + (size_t)(b * C_ + c) * NPIX;

    if (tid < 36) swl[tid / 9][tid % 9] = sw[(c * 4 + tid / 9) * 9 + tid % 9];

    float w0s = w_s_from_d[0];
    float wp  = w_prop[c];
    float inv_wp1 = 1.f / (wp + 1.f);
    float inv_sw  = 1.f / (sums[0] + EPSV);
    float b1 = wp * inv_wp1;

    // fill: stage 1 on the halo-1 grid (18x34); only direction 0 survives the
    // reference's argmax over identical stacked copies.
    for (int i = tid; i < TLY * TLX; i += 256) {
        int y = i / TLX, x = i - y * TLX;
        int gh = h0 - 1 + y, gw = w0 - 1 + x;
        if ((unsigned)gh < (unsigned)H_ && (unsigned)gw < (unsigned)W_) {
            float mn = 0.f, cmn = 0.f, mx = 0.f, cmx = 0.f;
            if (gh >= 1 && gw >= 1) {
                size_t q = (size_t)(gh - 1) * W_ + (gw - 1);
                mn = dbc[q]; cmn = cdbc[q];
            }
            if (gh < H_ - 1 && gw < W_ - 1) {
                size_t q = (size_t)(gh + 1) * W_ + (gw + 1);
                mx = dbc[q]; cmx = cdbc[q];
            }
            float r = __fdividef(mn, mx + EPSV);
            r = fminf(fmaxf(r, 0.f), 1.f);
            float sfd = r * fmaf(w0s, r, 1.f - w0s);
            float cfd = cmn * cmx;
            float a1 = cfd * sfd * inv_wp1;
            float c1 = cfd * inv_wp1;
            size_t gbase = (size_t)((b * C_ + c) * 4) * NPIX + (size_t)gh * W_ + gw;
            #pragma unroll
            for (int k = 0; k < 4; ++k) {
                float s_v  = s[gbase + (size_t)k * NPIX];
                float cs_v = cs[gbase + (size_t)k * NPIX];
                float t = b1 * cs_v;
                uv_[k][y][x] = make_float2(fmaf(t, s_v, a1), t + c1);
            }
        } else {
            #pragma unroll
            for (int k = 0; k < 4; ++k) uv_[k][y][x] = make_float2(0.f, 0.f);
        }
    }
    __syncthreads();

    // conv: per-pixel, one b64 read per tap; thread covers 2 pixels
    #pragma unroll
    for (int p = 0; p < 2; ++p) {
        int i = p * 256 + tid;
        int ty = i >> 5, tx = i & 31;
        unsigned hwx = 0, lwx = 0, hwy = 0, lwy = 0;
        #pragma unroll
        for (int k = 0; k < 4; ++k) {
            float nom = 0.f, den = 0.f;
            #pragma unroll
            for (int dy = 0; dy < 3; ++dy)
                #pragma unroll
                for (int dx = 0; dx < 3; ++dx) {
                    float2 P = uv_[k][ty + dy][tx + dx];
                    float wgt = swl[k][dy * 3 + dx];
                    nom = fmaf(wgt, P.x, nom);
                    den = fmaf(wgt, P.y, den);
                }
            float xv = nom * inv_sw;
            float yv = den * inv_sw;
            int qx = (int)rintf(xv * QS);
            int qy = (int)rintf(yv * QS);
            qx = qx < 0 ? 0 : (qx > 16383 ? 16383 : qx);
            qy = qy < 0 ? 0 : (qy > 16383 ? 16383 : qy);
            hwx |= (unsigned)(qx >> 7)   << (8 * k);
            lwx |= (unsigned)(qx & 127)  << (8 * k);
            hwy |= (unsigned)(qy >> 7)   << (8 * k);
            lwy |= (unsigned)(qy & 127)  << (8 * k);
        }
        int pb = (h0 + ty) * (W_ / 32) + (w0 >> 5);
        size_t base = (size_t)(b * PB + pb) * 16384 + (size_t)c * 256 + (size_t)tx * 8;
        *(uint2*)(XP + base) = make_uint2(hwx, lwx);
        *(uint2*)(YP + base) = make_uint2(hwy, lwy);
    }
}

// ---------------- stage 3: u8-limb MFMA GEMM, monolithic LDS stage ----------
// 512 threads (8 waves), tile 256 o x 32 pix. Panel = 32 KB (u8), staged with
// FOUR 8 KB global_load_lds ops [X03|Y03|X47|Y47]; two-phase counted vmcnt
// (6/20). Lanes expand u8 limbs H,L (ints <=127, exact in bf16) to fragments;
// accH = sum A*H, accL = sum Ah*L; result = (accH*128+accL)/16383.
// Transpose epilogue (full-line stores, R15/R17 A/B-proven).
__global__ __launch_bounds__(512) void k_stage3(
    const u8* __restrict__ XP, const u8* __restrict__ YP,
    const ushort_t* __restrict__ cwH, const ushort_t* __restrict__ cwL,
    const float* __restrict__ sums, float* __restrict__ out)
{
    __shared__ u8 stg[36864];   // 32 KB panel; 36 KB epilogue transpose overlay

    int tid  = threadIdx.x;
    int wave = tid >> 6, lane = tid & 63;
    int l15 = lane & 15, l4 = lane >> 4;
    int pb = blockIdx.x;
    int b  = blockIdx.y;
    int o0 = wave * 32;

    size_t tb = (size_t)(b * PB + pb) * 16384;   // u8 tile base

    f32x4 accnH[2][2] = {}, accnL[2][2] = {};
    f32x4 accdH[2][2] = {}, accdL[2][2] = {};
    uint2 wx[2][2], wy[2][2];    // [n][gg] raw u8 limbs
    s16x8 rAh[2][2], rAl[2][2];

#define MFMA __builtin_amdgcn_mfma_f32_16x16x32_bf16

#define LOADA(AB, KS) do {                                                        \
    _Pragma("unroll")                                                             \
    for (int m = 0; m < 2; ++m) {                                                 \
        size_t ro = (size_t)(o0 + m * 16 + l15) * C4 + (KS) * 32 + l4 * 8;        \
        rAh[AB][m] = *(const s16x8*)(cwH + ro);                                   \
        rAl[AB][m] = *(const s16x8*)(cwL + ro);                                   \
    } } while (0)

#define LOADB(KS) do {                                                            \
    int xo = ((KS) & 4) * 4096 + ((KS) & 3) * 2048;                               \
    _Pragma("unroll")                                                             \
    for (int n = 0; n < 2; ++n)                                                   \
        _Pragma("unroll")                                                         \
        for (int gg = 0; gg < 2; ++gg) {                                          \
            int o_ = xo + (l4 * 2 + gg) * 256 + (n * 16 + l15) * 8;               \
            wx[n][gg] = *(const uint2*)(stg + o_);                                \
            wy[n][gg] = *(const uint2*)(stg + o_ + 8192);                         \
        } } while (0)

#define COMPUTE(AB) do {                                                          \
    _Pragma("unroll")                                                             \
    for (int n = 0; n < 2; ++n) {                                                 \
        union { s16x8 v; unsigned u[4]; } bxh, bxl, byh, byl;                     \
        bxh.u[0] = bfp(wx[n][0].x, 0, 1); bxh.u[1] = bfp(wx[n][0].x, 2, 3);       \
        bxh.u[2] = bfp(wx[n][1].x, 0, 1); bxh.u[3] = bfp(wx[n][1].x, 2, 3);       \
        bxl.u[0] = bfp(wx[n][0].y, 0, 1); bxl.u[1] = bfp(wx[n][0].y, 2, 3);       \
        bxl.u[2] = bfp(wx[n][1].y, 0, 1); bxl.u[3] = bfp(wx[n][1].y, 2, 3);       \
        byh.u[0] = bfp(wy[n][0].x, 0, 1); byh.u[1] = bfp(wy[n][0].x, 2, 3);       \
        byh.u[2] = bfp(wy[n][1].x, 0, 1); byh.u[3] = bfp(wy[n][1].x, 2, 3);       \
        byl.u[0] = bfp(wy[n][0].y, 0, 1); byl.u[1] = bfp(wy[n][0].y, 2, 3);       \
        byl.u[2] = bfp(wy[n][1].y, 0, 1); byl.u[3] = bfp(wy[n][1].y, 2, 3);       \
        _Pragma("unroll")                                                         \
        for (int m = 0; m < 2; ++m) {                                             \
            accnH[m][n] = MFMA(rAh[AB][m], bxh.v, accnH[m][n], 0, 0, 0);          \
            accnH[m][n] = MFMA(rAl[AB][m], bxh.v, accnH[m][n], 0, 0, 0);          \
            accnL[m][n] = MFMA(rAh[AB][m], bxl.v, accnL[m][n], 0, 0, 0);          \
            accdH[m][n] = MFMA(rAh[AB][m], byh.v, accdH[m][n], 0, 0, 0);          \
            accdH[m][n] = MFMA(rAl[AB][m], byh.v, accdH[m][n], 0, 0, 0);          \
            accdL[m][n] = MFMA(rAh[AB][m], byl.v, accdL[m][n], 0, 0, 0);          \
        } } } while (0)

    // prologue: 4 STAGE ops (8 KB each: X03, Y03, X47, Y47), then A0
    async_ld16(XP + tb +        (size_t)tid * 16, stg +         tid * 16);
    async_ld16(YP + tb +        (size_t)tid * 16, stg +  8192 + tid * 16);
    async_ld16(XP + tb + 8192 + (size_t)tid * 16, stg + 16384 + tid * 16);
    async_ld16(YP + tb + 8192 + (size_t)tid * 16, stg + 24576 + tid * 16);
    __builtin_amdgcn_sched_barrier(0);
    LOADA(0, 0);
    __builtin_amdgcn_sched_barrier(0);

    // X03+Y03 retired (8 issued, <=6 outstanding -> oldest 2 done)
    asm volatile("s_waitcnt vmcnt(6)" ::: "memory");
    __builtin_amdgcn_s_barrier();
    __builtin_amdgcn_sched_barrier(0);

    LOADA(1, 1); LOADB(0); COMPUTE(0);
    LOADA(0, 2); LOADB(1); COMPUTE(1);
    LOADA(1, 3); LOADB(2); COMPUTE(0);
    LOADA(0, 4); LOADB(3); COMPUTE(1);

    // 24 issued; all 4 STAGE retired (<=20 outstanding -> oldest 4 done)
    asm volatile("s_waitcnt vmcnt(20)" ::: "memory");
    __builtin_amdgcn_s_barrier();
    __builtin_amdgcn_sched_barrier(0);

    LOADA(1, 5); LOADB(4); COMPUTE(0);
    LOADA(0, 6); LOADB(5); COMPUTE(1);
    LOADA(1, 7); LOADB(6); COMPUTE(0);
    LOADB(7); COMPUTE(1);

#undef COMPUTE
#undef LOADB
#undef LOADA
#undef MFMA

    // -------- epilogue: limb fold + LDS transpose -> full-line stores --------
    float* ts = reinterpret_cast<float*>(stg);   // 256 x 36 floats = 36,864 B
    float inv_scw = sums ? 1.f / (sums[1] + EPSV) : 0.f;
    __syncthreads();   // all LOADB consumers of stg finished

    #pragma unroll
    for (int pass2 = 0; pass2 < 2; ++pass2) {
        #pragma unroll
        for (int m = 0; m < 2; ++m)
            #pragma unroll
            for (int n = 0; n < 2; ++n)
                #pragma unroll
                for (int r = 0; r < 4; ++r) {
                    int o = o0 + m * 16 + l4 * 4 + r;
                    float n2 = fmaf(accnH[m][n][r], 128.f, accnL[m][n][r]) * INVQS;
                    float d2 = fmaf(accdH[m][n][r], 128.f, accdL[m][n][r]) * INVQS;
                    float val = pass2 ? d2 * inv_scw : n2 / (d2 + EPSV);
                    ts[o * 36 + n * 16 + l15] = val;
                }
        __syncthreads();
        size_t gb = (pass2 ? NT : 0) + (size_t)b * C4 * NPIX + (size_t)pb * 32;
        int oo = tid >> 3, j = tid & 7;
        #pragma unroll
        for (int pass = 0; pass < 4; ++pass) {
            int o = pass * 64 + oo;
            f32x4 v = *(const f32x4*)&ts[o * 36 + j * 4];
            *(f32x4*)&out[gb + (size_t)o * NPIX + j * 4] = v;
        }
        if (pass2 == 0) __syncthreads();
    }
}

} // namespace

extern "C" void kernel_launch(void* const* d_in, const int* in_sizes, int n_in,
                              void* d_out, int out_size, void* d_ws, size_t ws_size,
                              hipStream_t stream) {
    const float* d    = (const float*)d_in[0];
    const float* cd   = (const float*)d_in[1];
    const float* s    = (const float*)d_in[2];
    const float* cs   = (const float*)d_in[3];
    const float* w_s  = (const float*)d_in[4];
    const float* wprp = (const float*)d_in[5];
    const float* cw   = (const float*)d_in[6];
    const float* sw   = (const float*)d_in[7];
    float* out = (float*)d_out;

    u8* XP = (u8*)d_ws;                        // 2*NT bytes
    u8* YP = XP + 2 * NT;                      // 2*NT bytes
    ushort_t* cwH = (ushort_t*)(YP + 2 * NT);
    ushort_t* cwL = cwH + C4 * C4;
    float* sums   = (float*)(cwL + C4 * C4);
    float* partial = sums + 2;

    k_prep<<<C4, 256, 0, stream>>>(cw, cwH, cwL, partial);
    k_sums2<<<1, 256, 0, stream>>>(sw, partial, sums);
    // 6 x 12 tiles per (b,c) = 9216 blocks
    k_stage12<<<dim3(B_ * C_ * (H_ / TILEH) * (W_ / TILEW)), 256, 0, stream>>>(
        d, cd, s, cs, w_s, wprp, sw, sums, XP, YP);
    k_stage3<<<dim3(PB, B_), 512, 0, stream>>>(XP, YP, cwH, cwL, sums, out);
}

// Round 20
// 180.573 us; speedup vs baseline: 1.6713x; 1.1909x over previous
//
#include <hip/hip_runtime.h>

namespace {

typedef unsigned short ushort_t;
typedef unsigned char u8;
typedef int i32x4 __attribute__((ext_vector_type(4)));
typedef float f32x4 __attribute__((ext_vector_type(4)));

constexpr int B_ = 2, C_ = 64, H_ = 192, W_ = 192;
constexpr int C4 = 256;
constexpr int NPIX = H_ * W_;                       // 36864
constexpr size_t NT = (size_t)B_ * C4 * NPIX;       // 18,874,368
constexpr int PB = NPIX / 32;                       // 1152 32-pixel blocks per batch
constexpr float EPSV = 1e-20f;
constexpr float QS = 16383.f;
constexpr float INVQS2 = 1.f / (16383.f * 16383.f);

constexpr int TILEW = 32, TILEH = 16;
constexpr int TLX = TILEW + 2;   // 34
constexpr int TLY = TILEH + 2;   // 18

__device__ __forceinline__ void async_ld16(const u8* g, u8* l) {
    __builtin_amdgcn_global_load_lds(
        (const __attribute__((address_space(1))) unsigned int*)g,
        (__attribute__((address_space(3))) unsigned int*)l, 16, 0, 0);
}

// ---------------- cw -> u8 limb pair (14-bit fixed point) + partial sums -----
__global__ __launch_bounds__(256) void k_prep(const float* __restrict__ cw,
                                              u8* __restrict__ cwAh,
                                              u8* __restrict__ cwAl,
                                              float* __restrict__ partial) {
    __shared__ float red[256];
    int tid = threadIdx.x;
    int i = blockIdx.x * 256 + tid;   // grid 256 -> 65536 = [o][c4] row-major
    float w = cw[i];
    int qa = (int)rintf(w * QS);
    qa = qa < 0 ? 0 : (qa > 16383 ? 16383 : qa);
    cwAh[i] = (u8)(qa >> 7);
    cwAl[i] = (u8)(qa & 127);
    red[tid] = w; __syncthreads();
    for (int s2 = 128; s2 > 0; s2 >>= 1) { if (tid < s2) red[tid] += red[tid + s2]; __syncthreads(); }
    if (tid == 0) partial[blockIdx.x] = red[0];
}

// ---------------- tiny final reduction: sw sum + cw partials ----------------
__global__ __launch_bounds__(256) void k_sums2(const float* __restrict__ sw,
                                               const float* __restrict__ partial,
                                               float* __restrict__ sums) {
    __shared__ float red[256];
    int tid = threadIdx.x;
    float a = 0.f;
    for (int i = tid; i < C4 * 9; i += 256) a += sw[i];
    red[tid] = a; __syncthreads();
    for (int s2 = 128; s2 > 0; s2 >>= 1) { if (tid < s2) red[tid] += red[tid + s2]; __syncthreads(); }
    if (tid == 0) sums[0] = red[0];
    __syncthreads();
    red[tid] = partial[tid]; __syncthreads();
    for (int s2 = 128; s2 > 0; s2 >>= 1) { if (tid < s2) red[tid] += red[tid + s2]; __syncthreads(); }
    if (tid == 0) sums[1] = red[0];
}

// ---------------- fused stage 1 + stage 2 (depthwise conv) — R19 proven ------
// 32x16 tile, 19.58 KB LDS, ONE barrier, float2-interleaved u/v; outputs
// quantized u8 limbs (q = rint(x*16383); H=q>>7, L=q&127).
// XP/YP layout (u8): tile (b,pb) at (b*PB+pb)*16384; per g: 256 B = 32 pix x
// {H0..H3, L0..L3}. 8 B per pixel -> uint2 stores.
__global__ __launch_bounds__(256) void k_stage12(
    const float* __restrict__ d, const float* __restrict__ cd,
    const float* __restrict__ s, const float* __restrict__ cs,
    const float* __restrict__ w_s_from_d, const float* __restrict__ w_prop,
    const float* __restrict__ sw, const float* __restrict__ sums,
    u8* __restrict__ XP, u8* __restrict__ YP)
{
    __shared__ float2 uv_[4][TLY][TLX];   // 19,584 B (u=.x, v=.y)
    __shared__ float swl[4][9];

    int tid = threadIdx.x;
    int blk = blockIdx.x;
    constexpr int TX = W_ / TILEW, TY = H_ / TILEH;   // 6 x 12
    int tx0 = blk % TX; blk /= TX;
    int ty0 = blk % TY; blk /= TY;
    int c = blk % C_;
    int b = blk / C_;
    int h0 = ty0 * TILEH, w0 = tx0 * TILEW;

    const float* dbc  = d  + (size_t)(b * C_ + c) * NPIX;
    const float* cdbc = cd + (size_t)(b * C_ + c) * NPIX;

    if (tid < 36) swl[tid / 9][tid % 9] = sw[(c * 4 + tid / 9) * 9 + tid % 9];

    float w0s = w_s_from_d[0];
    float wp  = w_prop[c];
    float inv_wp1 = 1.f / (wp + 1.f);
    float inv_sw  = 1.f / (sums[0] + EPSV);
    float b1 = wp * inv_wp1;

    // fill: stage 1 on the halo-1 grid (18x34); only direction 0 survives the
    // reference's argmax over identical stacked copies.
    for (int i = tid; i < TLY * TLX; i += 256) {
        int y = i / TLX, x = i - y * TLX;
        int gh = h0 - 1 + y, gw = w0 - 1 + x;
        if ((unsigned)gh < (unsigned)H_ && (unsigned)gw < (unsigned)W_) {
            float mn = 0.f, cmn = 0.f, mx = 0.f, cmx = 0.f;
            if (gh >= 1 && gw >= 1) {
                size_t q = (size_t)(gh - 1) * W_ + (gw - 1);
                mn = dbc[q]; cmn = cdbc[q];
            }
            if (gh < H_ - 1 && gw < W_ - 1) {
                size_t q = (size_t)(gh + 1) * W_ + (gw + 1);
                mx = dbc[q]; cmx = cdbc[q];
            }
            float r = __fdividef(mn, mx + EPSV);
            r = fminf(fmaxf(r, 0.f), 1.f);
            float sfd = r * fmaf(w0s, r, 1.f - w0s);
            float cfd = cmn * cmx;
            float a1 = cfd * sfd * inv_wp1;
            float c1 = cfd * inv_wp1;
            size_t gbase = (size_t)((b * C_ + c) * 4) * NPIX + (size_t)gh * W_ + gw;
            #pragma unroll
            for (int k = 0; k < 4; ++k) {
                float s_v  = s[gbase + (size_t)k * NPIX];
                float cs_v = cs[gbase + (size_t)k * NPIX];
                float t = b1 * cs_v;
                uv_[k][y][x] = make_float2(fmaf(t, s_v, a1), t + c1);
            }
        } else {
            #pragma unroll
            for (int k = 0; k < 4; ++k) uv_[k][y][x] = make_float2(0.f, 0.f);
        }
    }
    __syncthreads();

    // conv: per-pixel, one b64 read per tap; thread covers 2 pixels
    #pragma unroll
    for (int p = 0; p < 2; ++p) {
        int i = p * 256 + tid;
        int ty = i >> 5, tx = i & 31;
        unsigned hwx = 0, lwx = 0, hwy = 0, lwy = 0;
        #pragma unroll
        for (int k = 0; k < 4; ++k) {
            float nom = 0.f, den = 0.f;
            #pragma unroll
            for (int dy = 0; dy < 3; ++dy)
                #pragma unroll
                for (int dx = 0; dx < 3; ++dx) {
                    float2 P = uv_[k][ty + dy][tx + dx];
                    float wgt = swl[k][dy * 3 + dx];
                    nom = fmaf(wgt, P.x, nom);
                    den = fmaf(wgt, P.y, den);
                }
            float xv = nom * inv_sw;
            float yv = den * inv_sw;
            int qx = (int)rintf(xv * QS);
            int qy = (int)rintf(yv * QS);
            qx = qx < 0 ? 0 : (qx > 16383 ? 16383 : qx);
            qy = qy < 0 ? 0 : (qy > 16383 ? 16383 : qy);
            hwx |= (unsigned)(qx >> 7)   << (8 * k);
            lwx |= (unsigned)(qx & 127)  << (8 * k);
            hwy |= (unsigned)(qy >> 7)   << (8 * k);
            lwy |= (unsigned)(qy & 127)  << (8 * k);
        }
        int pb = (h0 + ty) * (W_ / 32) + (w0 >> 5);
        size_t base = (size_t)(b * PB + pb) * 16384 + (size_t)c * 256 + (size_t)tx * 8;
        *(uint2*)(XP + base) = make_uint2(hwx, lwx);
        *(uint2*)(YP + base) = make_uint2(hwy, lwy);
    }
}

// ---------------- stage 3: exact-i8 integer MFMA GEMM ------------------------
// 512 threads (8 waves), tile 256 o x 32 pix. Panel = 32 KB u8 (4 stage ops).
// mfma_i32_16x16x64_i8, K=64 x 4 k-steps; limbs: value = H*128+L, both <=127
// fit signed i8. acc trio: HH (x2^14), Mid = AhBl+AlBh (x2^7), LL (x1) — the
// integer GEMM is EXACT; only operand quantization remains. Fragment k-byte j
// maps to c4 = l4*16+j: B gathers 4 adjacent g-rows (identity mapping to R19's
// XP layout); A is cwAh/cwAl[o][c4] natural order (one b128 per m per limb).
// Two-phase counted vmcnt (6/12); transpose epilogue (full-line stores).
__global__ __launch_bounds__(512) void k_stage3(
    const u8* __restrict__ XP, const u8* __restrict__ YP,
    const u8* __restrict__ cwAh, const u8* __restrict__ cwAl,
    const float* __restrict__ sums, float* __restrict__ out)
{
    __shared__ u8 stg[36864];   // 32 KB panel; 36 KB epilogue transpose overlay

    int tid  = threadIdx.x;
    int wave = tid >> 6, lane = tid & 63;
    int l15 = lane & 15, l4 = lane >> 4;
    int pb = blockIdx.x;
    int b  = blockIdx.y;
    int o0 = wave * 32;

    size_t tb = (size_t)(b * PB + pb) * 16384;   // u8 tile base

    i32x4 aHH[2][2] = {}, aM[2][2] = {}, aLL[2][2] = {};
    i32x4 dHH[2][2] = {}, dM[2][2] = {}, dLL[2][2] = {};
    uint2 wx[2][4], wy[2][4];    // [n][g-row] raw limb words (.x = H, .y = L)
    i32x4 rAh[2][2], rAl[2][2];  // [bank][m]

#define MFMAI __builtin_amdgcn_mfma_i32_16x16x64_i8

#define LOADA(AB, KS) do {                                                        \
    _Pragma("unroll")                                                             \
    for (int m = 0; m < 2; ++m) {                                                 \
        size_t ro = (size_t)(o0 + m * 16 + l15) * C4 + (KS) * 64 + l4 * 16;       \
        rAh[AB][m] = *(const i32x4*)(cwAh + ro);                                  \
        rAl[AB][m] = *(const i32x4*)(cwAl + ro);                                  \
    } } while (0)

#define LOADB(KS) do {                                                            \
    int xo = (((KS) & 2) ? 16384 : 0) + (((KS) & 1) ? 4096 : 0)                   \
           + l4 * 1024 + l15 * 8;                                                 \
    _Pragma("unroll")                                                             \
    for (int n = 0; n < 2; ++n)                                                   \
        _Pragma("unroll")                                                         \
        for (int i = 0; i < 4; ++i) {                                             \
            wx[n][i] = *(const uint2*)(stg + xo + n * 128 + i * 256);             \
            wy[n][i] = *(const uint2*)(stg + xo + n * 128 + i * 256 + 8192);      \
        } } while (0)

#define COMPUTE(AB) do {                                                          \
    _Pragma("unroll")                                                             \
    for (int n = 0; n < 2; ++n) {                                                 \
        union { i32x4 v; unsigned u[4]; } BXh, BXl, BYh, BYl;                     \
        _Pragma("unroll")                                                         \
        for (int i = 0; i < 4; ++i) {                                             \
            BXh.u[i] = wx[n][i].x; BXl.u[i] = wx[n][i].y;                         \
            BYh.u[i] = wy[n][i].x; BYl.u[i] = wy[n][i].y;                         \
        }                                                                         \
        _Pragma("unroll")                                                         \
        for (int m = 0; m < 2; ++m) {                                             \
            aHH[m][n] = MFMAI(rAh[AB][m], BXh.v, aHH[m][n], 0, 0, 0);             \
            aM [m][n] = MFMAI(rAh[AB][m], BXl.v, aM [m][n], 0, 0, 0);             \
            aM [m][n] = MFMAI(rAl[AB][m], BXh.v, aM [m][n], 0, 0, 0);             \
            aLL[m][n] = MFMAI(rAl[AB][m], BXl.v, aLL[m][n], 0, 0, 0);             \
            dHH[m][n] = MFMAI(rAh[AB][m], BYh.v, dHH[m][n], 0, 0, 0);             \
            dM [m][n] = MFMAI(rAh[AB][m], BYl.v, dM [m][n], 0, 0, 0);             \
            dM [m][n] = MFMAI(rAl[AB][m], BYh.v, dM [m][n], 0, 0, 0);             \
            dLL[m][n] = MFMAI(rAl[AB][m], BYl.v, dLL[m][n], 0, 0, 0);             \
        } } } while (0)

    // prologue: 4 STAGE ops (8 KB each: Xlo, Ylo, Xhi, Yhi), then A bank0 (ks0)
    async_ld16(XP + tb +        (size_t)tid * 16, stg +         tid * 16);
    async_ld16(YP + tb +        (size_t)tid * 16, stg +  8192 + tid * 16);
    async_ld16(XP + tb + 8192 + (size_t)tid * 16, stg + 16384 + tid * 16);
    async_ld16(YP + tb + 8192 + (size_t)tid * 16, stg + 24576 + tid * 16);
    __builtin_amdgcn_sched_barrier(0);
    LOADA(0, 0);
    __builtin_amdgcn_sched_barrier(0);

    // Xlo+Ylo retired (8 issued, <=6 outstanding -> oldest 2 done)
    asm volatile("s_waitcnt vmcnt(6)" ::: "memory");
    __builtin_amdgcn_s_barrier();
    __builtin_amdgcn_sched_barrier(0);

    LOADA(1, 1); LOADB(0); COMPUTE(0);
    LOADA(0, 2); LOADB(1); COMPUTE(1);

    // 16 issued; all 4 STAGE retired (<=12 outstanding -> oldest 4 done)
    asm volatile("s_waitcnt vmcnt(12)" ::: "memory");
    __builtin_amdgcn_s_barrier();
    __builtin_amdgcn_sched_barrier(0);

    LOADA(1, 3); LOADB(2); COMPUTE(0);
    LOADB(3); COMPUTE(1);

#undef COMPUTE
#undef LOADB
#undef LOADA
#undef MFMAI

    // -------- epilogue: limb fold + LDS transpose -> full-line stores --------
    float* ts = reinterpret_cast<float*>(stg);   // 256 x 36 floats = 36,864 B
    float inv_scw = 1.f / (sums[1] + EPSV);
    __syncthreads();   // all LOADB consumers of stg finished

    #pragma unroll
    for (int pass2 = 0; pass2 < 2; ++pass2) {
        #pragma unroll
        for (int m = 0; m < 2; ++m)
            #pragma unroll
            for (int n = 0; n < 2; ++n)
                #pragma unroll
                for (int r = 0; r < 4; ++r) {
                    int o = o0 + m * 16 + l4 * 4 + r;
                    float n2 = fmaf((float)aHH[m][n][r], 16384.f,
                               fmaf((float)aM[m][n][r], 128.f,
                                    (float)aLL[m][n][r])) * INVQS2;
                    float d2 = fmaf((float)dHH[m][n][r], 16384.f,
                               fmaf((float)dM[m][n][r], 128.f,
                                    (float)dLL[m][n][r])) * INVQS2;
                    float val = pass2 ? d2 * inv_scw : n2 / (d2 + EPSV);
                    ts[o * 36 + n * 16 + l15] = val;
                }
        __syncthreads();
        size_t gb = (pass2 ? NT : 0) + (size_t)b * C4 * NPIX + (size_t)pb * 32;
        int oo = tid >> 3, j = tid & 7;
        #pragma unroll
        for (int pass = 0; pass < 4; ++pass) {
            int o = pass * 64 + oo;
            f32x4 v = *(const f32x4*)&ts[o * 36 + j * 4];
            *(f32x4*)&out[gb + (size_t)o * NPIX + j * 4] = v;
        }
        if (pass2 == 0) __syncthreads();
    }
}

} // namespace

extern "C" void kernel_launch(void* const* d_in, const int* in_sizes, int n_in,
                              void* d_out, int out_size, void* d_ws, size_t ws_size,
                              hipStream_t stream) {
    const float* d    = (const float*)d_in[0];
    const float* cd   = (const float*)d_in[1];
    const float* s    = (const float*)d_in[2];
    const float* cs   = (const float*)d_in[3];
    const float* w_s  = (const float*)d_in[4];
    const float* wprp = (const float*)d_in[5];
    const float* cw   = (const float*)d_in[6];
    const float* sw   = (const float*)d_in[7];
    float* out = (float*)d_out;

    u8* XP = (u8*)d_ws;                        // 2*NT bytes
    u8* YP = XP + 2 * NT;                      // 2*NT bytes
    u8* cwAh = YP + 2 * NT;                    // 65,536 B
    u8* cwAl = cwAh + C4 * C4;                 // 65,536 B
    float* sums   = (float*)(cwAl + C4 * C4);
    float* partial = sums + 2;

    k_prep<<<C4, 256, 0, stream>>>(cw, cwAh, cwAl, partial);
    k_sums2<<<1, 256, 0, stream>>>(sw, partial, sums);
    // 6 x 12 tiles per (b,c) = 9216 blocks
    k_stage12<<<dim3(B_ * C_ * (H_ / TILEH) * (W_ / TILEW)), 256, 0, stream>>>(
        d, cd, s, cs, w_s, wprp, sw, sums, XP, YP);
    k_stage3<<<dim3(PB, B_), 512, 0, stream>>>(XP, YP, cwAh, cwAl, sums, out);
}

// Round 21
// 161.316 us; speedup vs baseline: 1.8708x; 1.1194x over previous
//
#include <hip/hip_runtime.h>

namespace {

typedef unsigned short ushort_t;
typedef unsigned char u8;
typedef int i32x4 __attribute__((ext_vector_type(4)));
typedef float f32x4 __attribute__((ext_vector_type(4)));

constexpr int B_ = 2, C_ = 64, H_ = 192, W_ = 192;
constexpr int C4 = 256;
constexpr int NPIX = H_ * W_;                       // 36864
constexpr size_t NT = (size_t)B_ * C4 * NPIX;       // 18,874,368
constexpr int PB = NPIX / 32;                       // 1152 32-pixel blocks per batch
constexpr float EPSV = 1e-20f;
constexpr float QS = 16383.f;
constexpr float INVQS2 = 1.f / (16383.f * 16383.f);

constexpr int TILEW = 32, TILEH = 16;
constexpr int TLX = TILEW + 2;   // 34
constexpr int TLY = TILEH + 2;   // 18

__device__ __forceinline__ void async_ld16(const u8* g, u8* l) {
    __builtin_amdgcn_global_load_lds(
        (const __attribute__((address_space(1))) unsigned int*)g,
        (__attribute__((address_space(3))) unsigned int*)l, 16, 0, 0);
}

// ---------------- cw -> u8 limb pair (14-bit fixed point) + partial sums -----
__global__ __launch_bounds__(256) void k_prep(const float* __restrict__ cw,
                                              u8* __restrict__ cwAh,
                                              u8* __restrict__ cwAl,
                                              float* __restrict__ partial) {
    __shared__ float red[256];
    int tid = threadIdx.x;
    int i = blockIdx.x * 256 + tid;   // grid 256 -> 65536 = [o][c4] row-major
    float w = cw[i];
    int qa = (int)rintf(w * QS);
    qa = qa < 0 ? 0 : (qa > 16383 ? 16383 : qa);
    cwAh[i] = (u8)(qa >> 7);
    cwAl[i] = (u8)(qa & 127);
    red[tid] = w; __syncthreads();
    for (int s2 = 128; s2 > 0; s2 >>= 1) { if (tid < s2) red[tid] += red[tid + s2]; __syncthreads(); }
    if (tid == 0) partial[blockIdx.x] = red[0];
}

// ---------------- tiny final reduction: sw sum + cw partials ----------------
__global__ __launch_bounds__(256) void k_sums2(const float* __restrict__ sw,
                                               const float* __restrict__ partial,
                                               float* __restrict__ sums) {
    __shared__ float red[256];
    int tid = threadIdx.x;
    float a = 0.f;
    for (int i = tid; i < C4 * 9; i += 256) a += sw[i];
    red[tid] = a; __syncthreads();
    for (int s2 = 128; s2 > 0; s2 >>= 1) { if (tid < s2) red[tid] += red[tid + s2]; __syncthreads(); }
    if (tid == 0) sums[0] = red[0];
    __syncthreads();
    red[tid] = partial[tid]; __syncthreads();
    for (int s2 = 128; s2 > 0; s2 >>= 1) { if (tid < s2) red[tid] += red[tid + s2]; __syncthreads(); }
    if (tid == 0) sums[1] = red[0];
}

// ---------------- fused stage 1 + stage 2 (depthwise conv) — R20 + T1 --------
// 32x16 tile, 19.58 KB LDS, ONE barrier, float2-interleaved u/v; quantized u8
// limb outputs. NEW: bijective XCD swizzle (9216 = 8*1152) so halo-sharing
// neighbor tiles live on the SAME XCD's L2 (cuts L3-eviction over-fetch).
__global__ __launch_bounds__(256) void k_stage12(
    const float* __restrict__ d, const float* __restrict__ cd,
    const float* __restrict__ s, const float* __restrict__ cs,
    const float* __restrict__ w_s_from_d, const float* __restrict__ w_prop,
    const float* __restrict__ sw, const float* __restrict__ sums,
    u8* __restrict__ XP, u8* __restrict__ YP)
{
    __shared__ float2 uv_[4][TLY][TLX];   // 19,584 B (u=.x, v=.y)
    __shared__ float swl[4][9];

    int tid = threadIdx.x;
    // XCD-bijective swizzle: consecutive hw blocks round-robin XCDs; give each
    // XCD a contiguous 1152-tile range (8 full (b,c) slabs of 72 tiles).
    int orig = blockIdx.x;
    int blk = (orig & 7) * 1152 + (orig >> 3);
    constexpr int TX = W_ / TILEW, TY = H_ / TILEH;   // 6 x 12
    int tx0 = blk % TX; blk /= TX;
    int ty0 = blk % TY; blk /= TY;
    int c = blk % C_;
    int b = blk / C_;
    int h0 = ty0 * TILEH, w0 = tx0 * TILEW;

    const float* dbc  = d  + (size_t)(b * C_ + c) * NPIX;
    const float* cdbc = cd + (size_t)(b * C_ + c) * NPIX;

    if (tid < 36) swl[tid / 9][tid % 9] = sw[(c * 4 + tid / 9) * 9 + tid % 9];

    float w0s = w_s_from_d[0];
    float wp  = w_prop[c];
    float inv_wp1 = 1.f / (wp + 1.f);
    float inv_sw  = 1.f / (sums[0] + EPSV);
    float b1 = wp * inv_wp1;

    // fill: stage 1 on the halo-1 grid (18x34); only direction 0 survives the
    // reference's argmax over identical stacked copies.
    for (int i = tid; i < TLY * TLX; i += 256) {
        int y = i / TLX, x = i - y * TLX;
        int gh = h0 - 1 + y, gw = w0 - 1 + x;
        if ((unsigned)gh < (unsigned)H_ && (unsigned)gw < (unsigned)W_) {
            float mn = 0.f, cmn = 0.f, mx = 0.f, cmx = 0.f;
            if (gh >= 1 && gw >= 1) {
                size_t q = (size_t)(gh - 1) * W_ + (gw - 1);
                mn = dbc[q]; cmn = cdbc[q];
            }
            if (gh < H_ - 1 && gw < W_ - 1) {
                size_t q = (size_t)(gh + 1) * W_ + (gw + 1);
                mx = dbc[q]; cmx = cdbc[q];
            }
            float r = __fdividef(mn, mx + EPSV);
            r = fminf(fmaxf(r, 0.f), 1.f);
            float sfd = r * fmaf(w0s, r, 1.f - w0s);
            float cfd = cmn * cmx;
            float a1 = cfd * sfd * inv_wp1;
            float c1 = cfd * inv_wp1;
            size_t gbase = (size_t)((b * C_ + c) * 4) * NPIX + (size_t)gh * W_ + gw;
            #pragma unroll
            for (int k = 0; k < 4; ++k) {
                float s_v  = s[gbase + (size_t)k * NPIX];
                float cs_v = cs[gbase + (size_t)k * NPIX];
                float t = b1 * cs_v;
                uv_[k][y][x] = make_float2(fmaf(t, s_v, a1), t + c1);
            }
        } else {
            #pragma unroll
            for (int k = 0; k < 4; ++k) uv_[k][y][x] = make_float2(0.f, 0.f);
        }
    }
    __syncthreads();

    // conv: per-pixel, one b64 read per tap; thread covers 2 pixels
    #pragma unroll
    for (int p = 0; p < 2; ++p) {
        int i = p * 256 + tid;
        int ty = i >> 5, tx = i & 31;
        unsigned hwx = 0, lwx = 0, hwy = 0, lwy = 0;
        #pragma unroll
        for (int k = 0; k < 4; ++k) {
            float nom = 0.f, den = 0.f;
            #pragma unroll
            for (int dy = 0; dy < 3; ++dy)
                #pragma unroll
                for (int dx = 0; dx < 3; ++dx) {
                    float2 P = uv_[k][ty + dy][tx + dx];
                    float wgt = swl[k][dy * 3 + dx];
                    nom = fmaf(wgt, P.x, nom);
                    den = fmaf(wgt, P.y, den);
                }
            float xv = nom * inv_sw;
            float yv = den * inv_sw;
            int qx = (int)rintf(xv * QS);
            int qy = (int)rintf(yv * QS);
            qx = qx < 0 ? 0 : (qx > 16383 ? 16383 : qx);
            qy = qy < 0 ? 0 : (qy > 16383 ? 16383 : qy);
            hwx |= (unsigned)(qx >> 7)   << (8 * k);
            lwx |= (unsigned)(qx & 127)  << (8 * k);
            hwy |= (unsigned)(qy >> 7)   << (8 * k);
            lwy |= (unsigned)(qy & 127)  << (8 * k);
        }
        int pb = (h0 + ty) * (W_ / 32) + (w0 >> 5);
        size_t base = (size_t)(b * PB + pb) * 16384 + (size_t)c * 256 + (size_t)tx * 8;
        *(uint2*)(XP + base) = make_uint2(hwx, lwx);
        *(uint2*)(YP + base) = make_uint2(hwy, lwy);
    }
}

// ---------------- stage 3: i8 integer MFMA GEMM (LL term dropped) ------------
// 512 threads (8 waves), tile 256 o x 32 pix. Panel = 32 KB u8 (4 stage ops).
// mfma_i32_16x16x64_i8, K=64 x 4 k-steps. value = H*128+L (limbs <=127, fit
// signed i8). accs: HH (x2^14), Mid = AhBl+AlBh (x2^7). LL term dropped:
// bias <= ~6e-5 relative (~1e-4 absolute on outputs) — frees 32 acc VGPRs and
// 2 MFMAs/k-step. Two-phase counted vmcnt (6/12); transpose epilogue.
__global__ __launch_bounds__(512) void k_stage3(
    const u8* __restrict__ XP, const u8* __restrict__ YP,
    const u8* __restrict__ cwAh, const u8* __restrict__ cwAl,
    const float* __restrict__ sums, float* __restrict__ out)
{
    __shared__ u8 stg[36864];   // 32 KB panel; 36 KB epilogue transpose overlay

    int tid  = threadIdx.x;
    int wave = tid >> 6, lane = tid & 63;
    int l15 = lane & 15, l4 = lane >> 4;
    int pb = blockIdx.x;
    int b  = blockIdx.y;
    int o0 = wave * 32;

    size_t tb = (size_t)(b * PB + pb) * 16384;   // u8 tile base

    i32x4 aHH[2][2] = {}, aM[2][2] = {};
    i32x4 dHH[2][2] = {}, dM[2][2] = {};
    uint2 wx[2][4], wy[2][4];    // [n][g-row] raw limb words (.x = H, .y = L)
    i32x4 rAh[2][2], rAl[2][2];  // [bank][m]

#define MFMAI __builtin_amdgcn_mfma_i32_16x16x64_i8

#define LOADA(AB, KS) do {                                                        \
    _Pragma("unroll")                                                             \
    for (int m = 0; m < 2; ++m) {                                                 \
        size_t ro = (size_t)(o0 + m * 16 + l15) * C4 + (KS) * 64 + l4 * 16;       \
        rAh[AB][m] = *(const i32x4*)(cwAh + ro);                                  \
        rAl[AB][m] = *(const i32x4*)(cwAl + ro);                                  \
    } } while (0)

#define LOADB(KS) do {                                                            \
    int xo = (((KS) & 2) ? 16384 : 0) + (((KS) & 1) ? 4096 : 0)                   \
           + l4 * 1024 + l15 * 8;                                                 \
    _Pragma("unroll")                                                             \
    for (int n = 0; n < 2; ++n)                                                   \
        _Pragma("unroll")                                                         \
        for (int i = 0; i < 4; ++i) {                                             \
            wx[n][i] = *(const uint2*)(stg + xo + n * 128 + i * 256);             \
            wy[n][i] = *(const uint2*)(stg + xo + n * 128 + i * 256 + 8192);      \
        } } while (0)

#define COMPUTE(AB) do {                                                          \
    _Pragma("unroll")                                                             \
    for (int n = 0; n < 2; ++n) {                                                 \
        union { i32x4 v; unsigned u[4]; } BXh, BXl, BYh, BYl;                     \
        _Pragma("unroll")                                                         \
        for (int i = 0; i < 4; ++i) {                                             \
            BXh.u[i] = wx[n][i].x; BXl.u[i] = wx[n][i].y;                         \
            BYh.u[i] = wy[n][i].x; BYl.u[i] = wy[n][i].y;                         \
        }                                                                         \
        _Pragma("unroll")                                                         \
        for (int m = 0; m < 2; ++m) {                                             \
            aHH[m][n] = MFMAI(rAh[AB][m], BXh.v, aHH[m][n], 0, 0, 0);             \
            aM [m][n] = MFMAI(rAh[AB][m], BXl.v, aM [m][n], 0, 0, 0);             \
            aM [m][n] = MFMAI(rAl[AB][m], BXh.v, aM [m][n], 0, 0, 0);             \
            dHH[m][n] = MFMAI(rAh[AB][m], BYh.v, dHH[m][n], 0, 0, 0);             \
            dM [m][n] = MFMAI(rAh[AB][m], BYl.v, dM [m][n], 0, 0, 0);             \
            dM [m][n] = MFMAI(rAl[AB][m], BYh.v, dM [m][n], 0, 0, 0);             \
        } } } while (0)

    // prologue: 4 STAGE ops (8 KB each: Xlo, Ylo, Xhi, Yhi), then A bank0 (ks0)
    async_ld16(XP + tb +        (size_t)tid * 16, stg +         tid * 16);
    async_ld16(YP + tb +        (size_t)tid * 16, stg +  8192 + tid * 16);
    async_ld16(XP + tb + 8192 + (size_t)tid * 16, stg + 16384 + tid * 16);
    async_ld16(YP + tb + 8192 + (size_t)tid * 16, stg + 24576 + tid * 16);
    __builtin_amdgcn_sched_barrier(0);
    LOADA(0, 0);
    __builtin_amdgcn_sched_barrier(0);

    // Xlo+Ylo retired (8 issued, <=6 outstanding -> oldest 2 done)
    asm volatile("s_waitcnt vmcnt(6)" ::: "memory");
    __builtin_amdgcn_s_barrier();
    __builtin_amdgcn_sched_barrier(0);

    LOADA(1, 1); LOADB(0); COMPUTE(0);
    LOADA(0, 2); LOADB(1); COMPUTE(1);

    // 16 issued; all 4 STAGE retired (<=12 outstanding -> oldest 4 done)
    asm volatile("s_waitcnt vmcnt(12)" ::: "memory");
    __builtin_amdgcn_s_barrier();
    __builtin_amdgcn_sched_barrier(0);

    LOADA(1, 3); LOADB(2); COMPUTE(0);
    LOADB(3); COMPUTE(1);

#undef COMPUTE
#undef LOADB
#undef LOADA
#undef MFMAI

    // -------- epilogue: limb fold + LDS transpose -> full-line stores --------
    float* ts = reinterpret_cast<float*>(stg);   // 256 x 36 floats = 36,864 B
    float inv_scw = 1.f / (sums[1] + EPSV);
    __syncthreads();   // all LOADB consumers of stg finished

    #pragma unroll
    for (int pass2 = 0; pass2 < 2; ++pass2) {
        #pragma unroll
        for (int m = 0; m < 2; ++m)
            #pragma unroll
            for (int n = 0; n < 2; ++n)
                #pragma unroll
                for (int r = 0; r < 4; ++r) {
                    int o = o0 + m * 16 + l4 * 4 + r;
                    float n2 = fmaf((float)aHH[m][n][r], 16384.f,
                                    (float)aM[m][n][r] * 128.f) * INVQS2;
                    float d2 = fmaf((float)dHH[m][n][r], 16384.f,
                                    (float)dM[m][n][r] * 128.f) * INVQS2;
                    float val = pass2 ? d2 * inv_scw : n2 / (d2 + EPSV);
                    ts[o * 36 + n * 16 + l15] = val;
                }
        __syncthreads();
        size_t gb = (pass2 ? NT : 0) + (size_t)b * C4 * NPIX + (size_t)pb * 32;
        int oo = tid >> 3, j = tid & 7;
        #pragma unroll
        for (int pass = 0; pass < 4; ++pass) {
            int o = pass * 64 + oo;
            f32x4 v = *(const f32x4*)&ts[o * 36 + j * 4];
            *(f32x4*)&out[gb + (size_t)o * NPIX + j * 4] = v;
        }
        if (pass2 == 0) __syncthreads();
    }
}

} // namespace

extern "C" void kernel_launch(void* const* d_in, const int* in_sizes, int n_in,
                              void* d_out, int out_size, void* d_ws, size_t ws_size,
                              hipStream_t stream) {
    const float* d    = (const float*)d_in[0];
    const float* cd   = (const float*)d_in[1];
    const float* s    = (const float*)d_in[2];
    const float* cs   = (const float*)d_in[3];
    const float* w_s  = (const float*)d_in[4];
    const float* wprp = (const float*)d_in[5];
    const float* cw   = (const float*)d_in[6];
    const float* sw   = (const float*)d_in[7];
    float* out = (float*)d_out;

    u8* XP = (u8*)d_ws;                        // 2*NT bytes
    u8* YP = XP + 2 * NT;                      // 2*NT bytes
    u8* cwAh = YP + 2 * NT;                    // 65,536 B
    u8* cwAl = cwAh + C4 * C4;                 // 65,536 B
    float* sums   = (float*)(cwAl + C4 * C4);
    float* partial = sums + 2;

    k_prep<<<C4, 256, 0, stream>>>(cw, cwAh, cwAl, partial);
    k_sums2<<<1, 256, 0, stream>>>(sw, partial, sums);
    // 6 x 12 tiles per (b,c) = 9216 blocks (XCD-swizzled inside the kernel)
    k_stage12<<<dim3(B_ * C_ * (H_ / TILEH) * (W_ / TILEW)), 256, 0, stream>>>(
        d, cd, s, cs, w_s, wprp, sw, sums, XP, YP);
    k_stage3<<<dim3(PB, B_), 512, 0, stream>>>(XP, YP, cwAh, cwAl, sums, out);
}